// Round 21
// baseline (386.429 us; speedup 1.0000x reference)
//
#include <hip/hip_runtime.h>
#include <hip/hip_bf16.h>
#include <math.h>

#define T_LEN  128
#define B_SZ   32
#define DMODEL 1024
#define H_N    8
#define DH_N   64
#define FD_N   256
#define R_N    4
#define NCRIT  1088
#define NREST  1568
#define NRESTP 1664
#define EPS_F  1e-6f
#define CH     16
#define CL     8

#define NB_CRIT 1088   // 8 XCD * 17 col * 8 row
#define NB_REST 832    // 8 XCD * 13 col * 8 row

#define LDP 76         // padded LDS stride (f16 elems): 152B = 38 dw -> conflict-free-ish

typedef __attribute__((ext_vector_type(8))) short bf16x8;
typedef __attribute__((ext_vector_type(8))) _Float16 f16x8;
typedef __attribute__((ext_vector_type(4))) float f32x4;

#define LO_SCALE 2048.0f
#define W_SCALE  32.0f

__device__ __forceinline__ float sigmoidf_(float x) { return 1.0f / (1.0f + __expf(-x)); }

// crit layout: [k 8x64][q 8x64][p1 8x4][p2 8x4]
__device__ __forceinline__ int map_crit(int j) {
    if (j < 512)  return (j >> 6) * 320 + (j & 63);
    if (j < 1024) { int t = j - 512;  return (t >> 6) * 320 + 64 + (t & 63); }
    if (j < 1056) { int t = j - 1024; return 2560 + (t >> 2) * 12 + (t & 3); }
    { int t = j - 1056; return 2560 + (t >> 2) * 12 + 4 + (t & 3); }
}
__device__ __forceinline__ int map_rest(int j) {
    if (j < 512)  return (j >> 6) * 320 + 128 + (j & 63);
    if (j < 1024) { int t = j - 512;  return (t >> 6) * 320 + 192 + (t & 63); }
    if (j < 1536) { int t = j - 1024; return (t >> 6) * 320 + 256 + (t & 63); }
    { int t = j - 1536; return 2560 + (t >> 2) * 12 + 8 + (t & 3); }
}

// ---------------- fused conversions ----------------
__global__ __launch_bounds__(256) void cvt_fused(
    const float* __restrict__ inputs, const float* __restrict__ Wf,
    const float* __restrict__ bfv, const float* __restrict__ Wp,
    _Float16* __restrict__ Xh, _Float16* __restrict__ Xl,
    _Float16* __restrict__ Wch, _Float16* __restrict__ Wcl,
    _Float16* __restrict__ Wrest_h, float* __restrict__ bias_rest,
    __hip_bfloat16* __restrict__ Wp_bf)
{
    const int bid = blockIdx.x;
    const int tid = threadIdx.x;
    if (bid < 2048) {
        const int n = T_LEN * B_SZ * DMODEL;
        int i = (bid * 256 + tid) * 4;
        const int stride = 2048 * 256 * 4;
        for (; i < n; i += stride) {
            float4 v = *(const float4*)(inputs + i);
            const float a[4] = {v.x, v.y, v.z, v.w};
            #pragma unroll
            for (int c = 0; c < 4; ++c) {
                const _Float16 h = (_Float16)a[c];
                Xh[i + c] = h;
                Xl[i + c] = (_Float16)((a[c] - (float)h) * LO_SCALE);
            }
        }
    } else if (bid < 3136) {
        const int j = bid - 2048;
        const int i = tid * 4;
        _Float16* dh = Wch + (size_t)j * 1024 + i;
        _Float16* dl = Wcl + (size_t)j * 1024 + i;
        float4 v = *(const float4*)(Wf + (size_t)map_crit(j) * 1024 + i);
        const float a[4] = {v.x * W_SCALE, v.y * W_SCALE, v.z * W_SCALE, v.w * W_SCALE};
        #pragma unroll
        for (int c = 0; c < 4; ++c) {
            const _Float16 h = (_Float16)a[c];
            dh[c] = h;
            dl[c] = (_Float16)((a[c] - (float)h) * LO_SCALE);
        }
    } else if (bid < 4800) {
        const int j = bid - 3136;
        const int i = tid * 4;
        _Float16* dst = Wrest_h + (size_t)j * 1024 + i;
        if (j < NREST) {
            const int wr = map_rest(j);
            float4 v = *(const float4*)(Wf + (size_t)wr * 1024 + i);
            dst[0] = (_Float16)v.x; dst[1] = (_Float16)v.y;
            dst[2] = (_Float16)v.z; dst[3] = (_Float16)v.w;
            if (tid == 0) bias_rest[j] = bfv[wr];
        } else {
            dst[0] = dst[1] = dst[2] = dst[3] = (_Float16)0.f;
            if (tid == 0) bias_rest[j] = 0.f;
        }
    } else {
        const int i = ((bid - 4800) * 256 + tid) * 4;
        float4 v = *(const float4*)(Wp + i);
        Wp_bf[i + 0] = __float2bfloat16(v.x);
        Wp_bf[i + 1] = __float2bfloat16(v.y);
        Wp_bf[i + 2] = __float2bfloat16(v.z);
        Wp_bf[i + 3] = __float2bfloat16(v.w);
    }
}

// ---------------- fused projection GEMM: crit | rest, col-outer per-XCD swizzle, padded LDS ----------------
__global__ __launch_bounds__(256) void gemm_proj(
    const _Float16* __restrict__ Xh, const _Float16* __restrict__ Xl,
    const _Float16* __restrict__ Wch, const _Float16* __restrict__ Wcl,
    const _Float16* __restrict__ Wrest_h,
    const float* __restrict__ bfv, const float* __restrict__ bias_rest,
    float* __restrict__ Cc, float* __restrict__ Cr)
{
    __shared__ __align__(16) char smem[38912];   // crit: 4x[64][76] f16; rest: [64][76]+[128][76]

    const int tid  = threadIdx.x;
    const int wave = tid >> 6, lane = tid & 63;
    const int lr = lane & 15;
    const int lk = (lane >> 4) * 8;
    const int lq = (lane >> 4) * 4;

    if (blockIdx.x < NB_CRIT) {
        _Float16 (*Ah)[LDP] = (_Float16(*)[LDP])(smem);
        _Float16 (*Al)[LDP] = (_Float16(*)[LDP])(smem + 9728);
        _Float16 (*Bh)[LDP] = (_Float16(*)[LDP])(smem + 19456);
        _Float16 (*Bl)[LDP] = (_Float16(*)[LDP])(smem + 29184);

        const int xcd  = blockIdx.x & 7;
        const int i2   = blockIdx.x >> 3;        // 0..135
        const int col0 = (i2 >> 3) * 64;         // col-tile slow (0..16)
        const int row0 = (xcd * 8 + (i2 & 7)) * 64;  // row-panel fast within XCD

        const int wr = (wave >> 1) * 32;
        const int wc = (wave & 1) * 32;
        const int sr = tid >> 2;
        const int sk = (tid & 3) * 16;

        const _Float16* xh = Xh + (size_t)(row0 + sr) * 1024 + sk;
        const _Float16* xl = Xl + (size_t)(row0 + sr) * 1024 + sk;
        const _Float16* wh = Wch + (size_t)(col0 + sr) * 1024 + sk;
        const _Float16* wl = Wcl + (size_t)(col0 + sr) * 1024 + sk;

        f32x4 accm[2][2] = {};
        f32x4 accc[2][2] = {};

        f16x8 rah0 = *(const f16x8*)(xh), rah1 = *(const f16x8*)(xh + 8);
        f16x8 ral0 = *(const f16x8*)(xl), ral1 = *(const f16x8*)(xl + 8);
        f16x8 rbh0 = *(const f16x8*)(wh), rbh1 = *(const f16x8*)(wh + 8);
        f16x8 rbl0 = *(const f16x8*)(wl), rbl1 = *(const f16x8*)(wl + 8);

        for (int k0 = 0; k0 < 1024; k0 += 64) {
            *(f16x8*)&Ah[sr][sk]     = rah0;
            *(f16x8*)&Ah[sr][sk + 8] = rah1;
            *(f16x8*)&Al[sr][sk]     = ral0;
            *(f16x8*)&Al[sr][sk + 8] = ral1;
            *(f16x8*)&Bh[sr][sk]     = rbh0;
            *(f16x8*)&Bh[sr][sk + 8] = rbh1;
            *(f16x8*)&Bl[sr][sk]     = rbl0;
            *(f16x8*)&Bl[sr][sk + 8] = rbl1;
            __syncthreads();
            if (k0 + 64 < 1024) {
                rah0 = *(const f16x8*)(xh + k0 + 64); rah1 = *(const f16x8*)(xh + k0 + 72);
                ral0 = *(const f16x8*)(xl + k0 + 64); ral1 = *(const f16x8*)(xl + k0 + 72);
                rbh0 = *(const f16x8*)(wh + k0 + 64); rbh1 = *(const f16x8*)(wh + k0 + 72);
                rbl0 = *(const f16x8*)(wl + k0 + 64); rbl1 = *(const f16x8*)(wl + k0 + 72);
            }
            #pragma unroll
            for (int kk0 = 0; kk0 < 64; kk0 += 32) {
                f16x8 ah[2], al[2], bh[2], bl[2];
                #pragma unroll
                for (int i = 0; i < 2; ++i) {
                    ah[i] = *(const f16x8*)&Ah[wr + i*16 + lr][kk0 + lk];
                    al[i] = *(const f16x8*)&Al[wr + i*16 + lr][kk0 + lk];
                }
                #pragma unroll
                for (int j = 0; j < 2; ++j) {
                    bh[j] = *(const f16x8*)&Bh[wc + j*16 + lr][kk0 + lk];
                    bl[j] = *(const f16x8*)&Bl[wc + j*16 + lr][kk0 + lk];
                }
                #pragma unroll
                for (int i = 0; i < 2; ++i)
                    #pragma unroll
                    for (int j = 0; j < 2; ++j) {
                        accm[i][j] = __builtin_amdgcn_mfma_f32_16x16x32_f16(ah[i], bh[j], accm[i][j], 0, 0, 0);
                        accc[i][j] = __builtin_amdgcn_mfma_f32_16x16x32_f16(ah[i], bl[j], accc[i][j], 0, 0, 0);
                        accc[i][j] = __builtin_amdgcn_mfma_f32_16x16x32_f16(al[i], bh[j], accc[i][j], 0, 0, 0);
                    }
            }
            __syncthreads();
        }

        #pragma unroll
        for (int j = 0; j < 2; ++j) {
            const int col = col0 + wc + j*16 + lr;
            const float bs = bfv[map_crit(col)];
            #pragma unroll
            for (int i = 0; i < 2; ++i) {
                const int rowb = row0 + wr + i*16 + lq;
                #pragma unroll
                for (int r = 0; r < 4; ++r) {
                    const float v = (accm[i][j][r] + accc[i][j][r] * (1.0f/LO_SCALE)) * (1.0f/W_SCALE) + bs;
                    Cc[(size_t)(rowb + r) * NCRIT + col] = v;
                }
            }
        }
    } else {
        _Float16 (*As)[LDP] = (_Float16(*)[LDP])(smem);
        _Float16 (*Bs)[LDP] = (_Float16(*)[LDP])(smem + 9728);

        const int rb   = blockIdx.x - NB_CRIT;
        const int xcd  = rb & 7;
        const int i2   = rb >> 3;                // 0..103
        const int col0 = (i2 >> 3) * 128;        // col-tile slow (0..12)
        const int row0 = (xcd * 8 + (i2 & 7)) * 64;

        const int wr = (wave >> 1) * 32;
        const int wc = (wave & 1) * 64;
        const int sr = tid >> 2;
        const int sk = (tid & 3) * 16;

        const _Float16* aptr  = Xh + (size_t)(row0 + sr) * 1024 + sk;
        const _Float16* bptr0 = Wrest_h + (size_t)(col0 + sr) * 1024 + sk;
        const _Float16* bptr1 = Wrest_h + (size_t)(col0 + 64 + sr) * 1024 + sk;

        f32x4 acc[2][4] = {};

        f16x8 ra0 = *(const f16x8*)(aptr),  ra1 = *(const f16x8*)(aptr + 8);
        f16x8 rb00 = *(const f16x8*)(bptr0), rb01 = *(const f16x8*)(bptr0 + 8);
        f16x8 rb10 = *(const f16x8*)(bptr1), rb11 = *(const f16x8*)(bptr1 + 8);

        for (int k0 = 0; k0 < 1024; k0 += 64) {
            *(f16x8*)&As[sr][sk]          = ra0;
            *(f16x8*)&As[sr][sk + 8]      = ra1;
            *(f16x8*)&Bs[sr][sk]          = rb00;
            *(f16x8*)&Bs[sr][sk + 8]      = rb01;
            *(f16x8*)&Bs[64 + sr][sk]     = rb10;
            *(f16x8*)&Bs[64 + sr][sk + 8] = rb11;
            __syncthreads();
            if (k0 + 64 < 1024) {
                ra0  = *(const f16x8*)(aptr + k0 + 64);  ra1  = *(const f16x8*)(aptr + k0 + 72);
                rb00 = *(const f16x8*)(bptr0 + k0 + 64); rb01 = *(const f16x8*)(bptr0 + k0 + 72);
                rb10 = *(const f16x8*)(bptr1 + k0 + 64); rb11 = *(const f16x8*)(bptr1 + k0 + 72);
            }
            #pragma unroll
            for (int kk0 = 0; kk0 < 64; kk0 += 32) {
                f16x8 af[2], bfr[4];
                #pragma unroll
                for (int i = 0; i < 2; ++i)
                    af[i] = *(const f16x8*)&As[wr + i*16 + lr][kk0 + lk];
                #pragma unroll
                for (int j = 0; j < 4; ++j)
                    bfr[j] = *(const f16x8*)&Bs[wc + j*16 + lr][kk0 + lk];
                #pragma unroll
                for (int i = 0; i < 2; ++i)
                    #pragma unroll
                    for (int j = 0; j < 4; ++j)
                        acc[i][j] = __builtin_amdgcn_mfma_f32_16x16x32_f16(af[i], bfr[j], acc[i][j], 0, 0, 0);
            }
            __syncthreads();
        }

        #pragma unroll
        for (int j = 0; j < 4; ++j) {
            const int col = col0 + wc + j*16 + lr;
            const float bs = bias_rest[col];
            #pragma unroll
            for (int i = 0; i < 2; ++i) {
                const int rowb = row0 + wr + i*16 + lq;
                #pragma unroll
                for (int r = 0; r < 4; ++r)
                    Cr[(size_t)(rowb + r) * NRESTP + col] = acc[i][j][r] + bs;
            }
        }
    }
}

// ---------------- output projection (bf16 MFMA, dbuf) ----------------
__global__ __launch_bounds__(256) void gemm_out(
    const __hip_bfloat16* __restrict__ A, const __hip_bfloat16* __restrict__ Bm,
    const float* __restrict__ bias, float* __restrict__ C)
{
    __shared__ __align__(16) short As[64][40];
    __shared__ __align__(16) short Bs[128][40];

    const int tid  = threadIdx.x;
    const int wave = tid >> 6, lane = tid & 63;
    const int row0 = blockIdx.y * 64;
    const int col0 = blockIdx.x * 128;
    const int K = H_N * DH_N;

    const int wr = (wave >> 1) * 32;
    const int wc = (wave & 1) * 64;
    const int lr = lane & 15;
    const int lk = (lane >> 4) * 8;
    const int lq = (lane >> 4) * 4;

    const int sr = tid >> 2;
    const int sk = (tid & 3) * 8;

    const short* aptr  = (const short*)A + (size_t)(row0 + sr) * K + sk;
    const short* bptr0 = (const short*)Bm + (size_t)(col0 + sr) * K + sk;
    const short* bptr1 = (const short*)Bm + (size_t)(col0 + 64 + sr) * K + sk;

    f32x4 acc[2][4] = {};

    bf16x8 ra  = *(const bf16x8*)(aptr);
    bf16x8 rb0 = *(const bf16x8*)(bptr0);
    bf16x8 rb1 = *(const bf16x8*)(bptr1);

    for (int k0 = 0; k0 < K; k0 += 32) {
        *(bf16x8*)&As[sr][sk]      = ra;
        *(bf16x8*)&Bs[sr][sk]      = rb0;
        *(bf16x8*)&Bs[64 + sr][sk] = rb1;
        __syncthreads();
        if (k0 + 32 < K) {
            ra  = *(const bf16x8*)(aptr + k0 + 32);
            rb0 = *(const bf16x8*)(bptr0 + k0 + 32);
            rb1 = *(const bf16x8*)(bptr1 + k0 + 32);
        }
        bf16x8 af[2], bfr[4];
        #pragma unroll
        for (int i = 0; i < 2; ++i)
            af[i] = *(const bf16x8*)&As[wr + i*16 + lr][lk];
        #pragma unroll
        for (int j = 0; j < 4; ++j)
            bfr[j] = *(const bf16x8*)&Bs[wc + j*16 + lr][lk];
        #pragma unroll
        for (int i = 0; i < 2; ++i)
            #pragma unroll
            for (int j = 0; j < 4; ++j)
                acc[i][j] = __builtin_amdgcn_mfma_f32_16x16x32_bf16(af[i], bfr[j], acc[i][j], 0, 0, 0);
        __syncthreads();
    }

    #pragma unroll
    for (int j = 0; j < 4; ++j) {
        const int col = col0 + wc + j*16 + lr;
        const float bs = bias[col];
        #pragma unroll
        for (int i = 0; i < 2; ++i) {
            const int rowb = row0 + wr + i*16 + lq;
            #pragma unroll
            for (int r = 0; r < 4; ++r)
                C[(size_t)(rowb + r) * DMODEL + col] = acc[i][j][r] + bs;
        }
    }
}

// ============ parallel scan (CH=16, CL=8) ============
// passA: feature-split — grid (B, CH, 2) x 256 threads; block z owns features z*256..z*256+255.
__global__ __launch_bounds__(256, 1)
void scan_passA(const float* __restrict__ pc, const float* __restrict__ pr,
                const int* __restrict__ term, const float* __restrict__ tick_in,
                float* __restrict__ SPk, float* __restrict__ SPv4, float* __restrict__ SPv1)
{
    const int b = blockIdx.x, c = blockIdx.y;
    const int ftid = blockIdx.z * 256 + threadIdx.x;   // 0..511
    const int w = ftid >> 6, lane = ftid & 63;
    const int t0 = c * CL;

    __shared__ __align__(16) float cos_s[CL][4];
    const float tick_b = tick_in[b];
    if (threadIdx.x < CL * 4) {
        const int lt = threadIdx.x >> 2, r = threadIdx.x & 3;
        const float PI_F = 3.14159265358979323846f;
        const float omega[4] = {-PI_F, -PI_F/3.0f, PI_F/3.0f, PI_F};
        cos_s[lt][r] = cosf(((float)(t0 + lt + 1) + tick_b) * omega[r]);
    }
    __syncthreads();

    float Sk[4][4] = {}, Ss[4] = {}, Sv[4] = {};
    float Pd[4] = {1.f, 1.f, 1.f, 1.f};
    float Pv = 1.f;

    float ck, cv, cbt, cg, ctm; float4 cp1, cp3;
    auto loadA = [&](int lt, float& k, float& v, float& bt, float& g,
                     float4& p1, float4& p3, float& tm) {
        const int t = t0 + ((lt < CL) ? lt : CL - 1);
        const float* Pc = pc + (size_t)(t * B_SZ + b) * NCRIT;
        const float* Pr = pr + (size_t)(t * B_SZ + b) * NRESTP;
        k  = Pc[w*64 + lane];
        p1 = *(const float4*)(Pc + 1024 + w*4);
        v  = Pr[w*64 + lane];
        bt = Pr[512 + w*64 + lane];
        g  = Pr[1024 + w*64 + lane];
        p3 = *(const float4*)(Pr + 1536 + w*4);
        tm = (float)term[t * B_SZ + b];
    };
    loadA(0, ck, cv, cbt, cg, cp1, cp3, ctm);

    for (int lt = 0; lt < CL; ++lt) {
        float nk, nv, nbt, ng, ntm; float4 np1, np3;
        loadA(lt + 1, nk, nv, nbt, ng, np1, np3, ntm);

        const float mask = 1.f - ctm;
        const float4 cs4 = *(const float4*)&cos_s[lt][0];
        const float cosr[4] = {cs4.x, cs4.y, cs4.z, cs4.w};
        const float rk = fmaxf(ck, 0.f);
        const float sg = sigmoidf_(cg);
        const float p1v[4] = {cp1.x, cp1.y, cp1.z, cp1.w};
        const float p3v[4] = {cp3.x, cp3.y, cp3.z, cp3.w};

        #pragma unroll
        for (int e = 0; e < 4; ++e) {
            const float psi = rk * fmaxf(p1v[e], 0.f);
            const float gf  = sg * sigmoidf_(p3v[e]);
            const float kg  = psi * gf;
            const float dg  = (1.f - gf) * mask;
            #pragma unroll
            for (int r = 0; r < 4; ++r)
                Sk[r][e] = dg * Sk[r][e] + kg * cosr[r];
            Ss[e] = dg * Ss[e] + kg;
            Pd[e] *= dg;
        }
        const float bb = sigmoidf_(cbt);
        const float vg = cv * bb;
        const float db = (1.f - bb) * mask;
        #pragma unroll
        for (int r = 0; r < 4; ++r) Sv[r] = db * Sv[r] + vg * cosr[r];
        Pv *= db;

        ck = nk; cv = nv; cbt = nbt; cg = ng; cp1 = np1; cp3 = np3; ctm = ntm;
    }

    float* K = SPk + ((size_t)(b * CH + c) * 512 + ftid) * 24;
    #pragma unroll
    for (int r = 0; r < 4; ++r)
        *(float4*)(K + r*4) = make_float4(Sk[r][0], Sk[r][1], Sk[r][2], Sk[r][3]);
    *(float4*)(K + 16) = make_float4(Pd[0], Pd[1], Pd[2], Pd[3]);
    *(float4*)(K + 20) = make_float4(Ss[0], Ss[1], Ss[2], Ss[3]);
    *(float4*)(SPv4 + ((size_t)(b * CH + c) * 512 + ftid) * 4) =
        make_float4(Sv[0], Sv[1], Sv[2], Sv[3]);
    SPv1[(size_t)(b * CH + c) * 512 + ftid] = Pv;
}

// passB: feature-parallel carry combine (256 blocks, reg-prefetch)
__global__ __launch_bounds__(64, 4)
void scan_passB(float* __restrict__ SPk, float* __restrict__ SPv4,
                const float* __restrict__ SPv1,
                const float* __restrict__ fk_prev, const float* __restrict__ fv_prev,
                const float* __restrict__ fs_prev, const float* __restrict__ tick_in,
                float* __restrict__ out_fk, float* __restrict__ out_fv,
                float* __restrict__ out_fs, float* __restrict__ out_tick)
{
    const int b = blockIdx.x, w = blockIdx.y;
    const int lane = threadIdx.x;
    const int ftid = w * 64 + lane;
    const int f0 = lane << 2;

    float yk[4][4], ys[4], yv[4];
    #pragma unroll
    for (int r = 0; r < 4; ++r) {
        const float4 kk = *(const float4*)(fk_prev + (((size_t)b * R_N + r) * H_N + w) * FD_N + f0);
        yk[r][0] = kk.x; yk[r][1] = kk.y; yk[r][2] = kk.z; yk[r][3] = kk.w;
        yv[r] = fv_prev[(((size_t)b * R_N + r) * H_N + w) * DH_N + lane];
    }
    {
        const float4 ss = *(const float4*)(fs_prev + ((size_t)b * H_N + w) * FD_N + f0);
        ys[0] = ss.x; ys[1] = ss.y; ys[2] = ss.z; ys[3] = ss.w;
    }

    const size_t stride = (size_t)512 * 24;
    const size_t strideV = (size_t)512 * 4;
    float* K0 = SPk + ((size_t)(b * CH) * 512 + ftid) * 24;
    float* V0 = SPv4 + ((size_t)(b * CH) * 512 + ftid) * 4;
    const float* P0 = SPv1 + (size_t)(b * CH) * 512 + ftid;

    float4 S0 = *(float4*)(K0 + 0),  S1 = *(float4*)(K0 + 4);
    float4 S2 = *(float4*)(K0 + 8),  S3 = *(float4*)(K0 + 12);
    float4 P4 = *(float4*)(K0 + 16), Q4 = *(float4*)(K0 + 20);
    float4 Sv4 = *(float4*)V0;
    float  Pv  = P0[0];

    for (int c = 0; c < CH; ++c) {
        float* K = K0 + (size_t)c * stride;
        float* V = V0 + (size_t)c * strideV;

        const float4 cS0 = S0, cS1 = S1, cS2 = S2, cS3 = S3, cP4 = P4, cQ4 = Q4, cSv = Sv4;
        const float cPv = Pv;

        if (c + 1 < CH) {
            float* Kn = K0 + (size_t)(c + 1) * stride;
            float* Vn = V0 + (size_t)(c + 1) * strideV;
            S0 = *(float4*)(Kn + 0);  S1 = *(float4*)(Kn + 4);
            S2 = *(float4*)(Kn + 8);  S3 = *(float4*)(Kn + 12);
            P4 = *(float4*)(Kn + 16); Q4 = *(float4*)(Kn + 20);
            Sv4 = *(float4*)Vn;
            Pv  = P0[(size_t)(c + 1) * 512];
        }

        *(float4*)(K + 0)  = make_float4(yk[0][0], yk[0][1], yk[0][2], yk[0][3]);
        *(float4*)(K + 4)  = make_float4(yk[1][0], yk[1][1], yk[1][2], yk[1][3]);
        *(float4*)(K + 8)  = make_float4(yk[2][0], yk[2][1], yk[2][2], yk[2][3]);
        *(float4*)(K + 12) = make_float4(yk[3][0], yk[3][1], yk[3][2], yk[3][3]);
        *(float4*)(K + 20) = make_float4(ys[0], ys[1], ys[2], ys[3]);
        *(float4*)V        = make_float4(yv[0], yv[1], yv[2], yv[3]);

        const float S[4][4] = {{cS0.x,cS0.y,cS0.z,cS0.w}, {cS1.x,cS1.y,cS1.z,cS1.w},
                               {cS2.x,cS2.y,cS2.z,cS2.w}, {cS3.x,cS3.y,cS3.z,cS3.w}};
        const float Pd[4] = {cP4.x, cP4.y, cP4.z, cP4.w};
        const float Ssv[4] = {cQ4.x, cQ4.y, cQ4.z, cQ4.w};
        const float Svv[4] = {cSv.x, cSv.y, cSv.z, cSv.w};
        #pragma unroll
        for (int e = 0; e < 4; ++e) {
            #pragma unroll
            for (int r = 0; r < 4; ++r)
                yk[r][e] = S[r][e] + Pd[e] * yk[r][e];
            ys[e] = Ssv[e] + Pd[e] * ys[e];
        }
        #pragma unroll
        for (int r = 0; r < 4; ++r)
            yv[r] = Svv[r] + cPv * yv[r];
    }

    #pragma unroll
    for (int r = 0; r < 4; ++r) {
        *(float4*)(out_fk + (((size_t)b * R_N + r) * H_N + w) * FD_N + f0) =
            make_float4(yk[r][0], yk[r][1], yk[r][2], yk[r][3]);
        out_fv[(((size_t)b * R_N + r) * H_N + w) * DH_N + lane] = yv[r];
    }
    *(float4*)(out_fs + ((size_t)b * H_N + w) * FD_N + f0) =
        make_float4(ys[0], ys[1], ys[2], ys[3]);
    if (w == 0 && lane == 0) out_tick[b] = tick_in[b] + (float)T_LEN;
}

struct PF {
    float k[4], q[4], v[4], bt[4], g[4], tm[4];
    float4 p1[4], p2[4], p3[4];
};

__global__ __launch_bounds__(512, 1)
void scan_passC(const float* __restrict__ pc, const float* __restrict__ pr,
                const int* __restrict__ term, const float* __restrict__ tick_in,
                const float* __restrict__ SPk, const float* __restrict__ SPv4,
                __hip_bfloat16* __restrict__ attn)
{
    const int b = blockIdx.x, c = blockIdx.y;
    const int tid = threadIdx.x, w = tid >> 6, lane = tid & 63;
    const int tc0 = c * CL;

    __shared__ float red[2][4][8][4];
    __shared__ __align__(16) float cos_s[CL][4];

    const float tick_b = tick_in[b];
    if (tid < CL * 4) {
        const int lt = tid >> 2, r = tid & 3;
        const float PI_F = 3.14159265358979323846f;
        const float omega[4] = {-PI_F, -PI_F/3.0f, PI_F/3.0f, PI_F};
        cos_s[lt][r] = cosf(((float)(tc0 + lt + 1) + tick_b) * omega[r]);
    }

    float fk[4][4], fsv[4], fv[4];
    {
        const float* K = SPk + ((size_t)(b * CH + c) * 512 + tid) * 24;
        #pragma unroll
        for (int r = 0; r < 4; ++r) {
            const float4 kk = *(const float4*)(K + r*4);
            fk[r][0] = kk.x; fk[r][1] = kk.y; fk[r][2] = kk.z; fk[r][3] = kk.w;
        }
        const float4 s4 = *(const float4*)(K + 20);
        fsv[0] = s4.x; fsv[1] = s4.y; fsv[2] = s4.z; fsv[3] = s4.w;
        const float4 v4 = *(const float4*)(SPv4 + ((size_t)(b * CH + c) * 512 + tid) * 4);
        fv[0] = v4.x; fv[1] = v4.y; fv[2] = v4.z; fv[3] = v4.w;
    }

    auto prefetch = [&](PF& dst, int lt0) {
        #pragma unroll
        for (int s = 0; s < 4; ++s) {
            int lt = lt0 + s; lt = (lt < CL) ? lt : CL - 1;
            const int t = tc0 + lt;
            const float* Pc = pc + (size_t)(t * B_SZ + b) * NCRIT;
            const float* Pr = pr + (size_t)(t * B_SZ + b) * NRESTP;
            dst.k[s]  = Pc[w*64 + lane];
            dst.q[s]  = Pc[512 + w*64 + lane];
            dst.p1[s] = *(const float4*)(Pc + 1024 + w*4);
            dst.p2[s] = *(const float4*)(Pc + 1056 + w*4);
            dst.v[s]  = Pr[w*64 + lane];
            dst.bt[s] = Pr[512 + w*64 + lane];
            dst.g[s]  = Pr[1024 + w*64 + lane];
            dst.p3[s] = *(const float4*)(Pr + 1536 + w*4);
            dst.tm[s] = (float)term[t * B_SZ + b];
        }
    };

    auto round_body = [&](const PF& cur, int lt0, int P) {
        float sc[4][4], nr[4], fvs[4][4];
        #pragma unroll
        for (int s = 0; s < 4; ++s) {
            const float mask = 1.f - cur.tm[s];
            const float4 cs = *(const float4*)&cos_s[lt0 + s][0];
            const float cosr[4] = {cs.x, cs.y, cs.z, cs.w};
            const float rk = fmaxf(cur.k[s], 0.f);
            const float rq = fmaxf(cur.q[s], 0.f);
            const float sg = sigmoidf_(cur.g[s]);
            const float p1v[4] = {cur.p1[s].x, cur.p1[s].y, cur.p1[s].z, cur.p1[s].w};
            const float p2v[4] = {cur.p2[s].x, cur.p2[s].y, cur.p2[s].z, cur.p2[s].w};
            const float p3v[4] = {cur.p3[s].x, cur.p3[s].y, cur.p3[s].z, cur.p3[s].w};
            float phi[4], kg[4], dgv[4];
            float np = 0.f;
            #pragma unroll
            for (int e = 0; e < 4; ++e) {
                const float psi = rk * fmaxf(p1v[e], 0.f);
                phi[e] = rq * fmaxf(p2v[e], 0.f);
                const float gf = sg * sigmoidf_(p3v[e]);
                kg[e] = psi * gf;
                dgv[e] = (1.f - gf) * mask;
                fsv[e] = dgv[e] * fsv[e] + kg[e];
                np += fsv[e] * phi[e];
            }
            nr[s] = np;
            #pragma unroll
            for (int r = 0; r < R_N; ++r) {
                float ss = 0.f;
                #pragma unroll
                for (int e = 0; e < 4; ++e) {
                    fk[r][e] = dgv[e] * fk[r][e] + kg[e] * cosr[r];
                    ss += fk[r][e] * phi[e];
                }
                sc[s][r] = ss;
            }
            const float bb = sigmoidf_(cur.bt[s]);
            const float vg = cur.v[s] * bb;
            const float db = (1.f - bb) * mask;
            #pragma unroll
            for (int r = 0; r < R_N; ++r) { fv[r] = db * fv[r] + vg * cosr[r]; fvs[s][r] = fv[r]; }
        }
        #pragma unroll
        for (int off = 32; off >= 1; off >>= 1) {
            #pragma unroll
            for (int s = 0; s < 4; ++s) {
                #pragma unroll
                for (int r = 0; r < 4; ++r) sc[s][r] += __shfl_xor(sc[s][r], off);
                nr[s] += __shfl_xor(nr[s], off);
            }
        }
        if (lane == 0) {
            #pragma unroll
            for (int s = 0; s < 4; ++s)
                *(float4*)&red[P][s][w][0] = make_float4(sc[s][0], sc[s][1], sc[s][2], sc[s][3]);
        }
        __syncthreads();
        #pragma unroll
        for (int s = 0; s < 4; ++s) {
            float s0 = 0.f, s1 = 0.f, s2 = 0.f, s3 = 0.f;
            #pragma unroll
            for (int ww = 0; ww < 8; ++ww) {
                const float4 rv = *(const float4*)&red[P][s][ww][0];
                s0 += rv.x; s1 += rv.y; s2 += rv.z; s3 += rv.w;
            }
            const float kv = fvs[s][0]*s0 + fvs[s][1]*s1 + fvs[s][2]*s2 + fvs[s][3]*s3;
            attn[((size_t)(tc0 + lt0 + s) * B_SZ + b) * (H_N * DH_N) + tid] =
                __float2bfloat16(kv / (2.0f * R_N * nr[s] + EPS_F));
        }
    };

    PF Abuf, Bbuf;
    prefetch(Abuf, 0);
    __syncthreads();

    for (int lt0 = 0; lt0 < CL; lt0 += 8) {
        prefetch(Bbuf, lt0 + 4);
        round_body(Abuf, lt0, 0);
        prefetch(Abuf, lt0 + 8);
        round_body(Bbuf, lt0 + 4, 1);
    }
}

extern "C" void kernel_launch(void* const* d_in, const int* in_sizes, int n_in,
                              void* d_out, int out_size, void* d_ws, size_t ws_size,
                              hipStream_t stream)
{
    const float* inputs  = (const float*)d_in[0];
    const int*   term    = (const int*)  d_in[1];
    const float* fk_prev = (const float*)d_in[2];
    const float* fv_prev = (const float*)d_in[3];
    const float* fs_prev = (const float*)d_in[4];
    const float* tick    = (const float*)d_in[5];
    const float* Wf      = (const float*)d_in[6];
    const float* bf      = (const float*)d_in[7];
    const float* Wp      = (const float*)d_in[8];
    const float* bp      = (const float*)d_in[9];

    float* out      = (float*)d_out;
    float* out_fk   = out    + (size_t)T_LEN * B_SZ * DMODEL;
    float* out_fv   = out_fk + (size_t)B_SZ * R_N * H_N * FD_N;
    float* out_fs   = out_fv + (size_t)B_SZ * R_N * H_N * DH_N;
    float* out_tick = out_fs + (size_t)B_SZ * H_N * FD_N;

    char* ws = (char*)d_ws;
    float* proj_crit = (float*)ws;                       // 17.8 MB
    ws += (size_t)T_LEN * B_SZ * NCRIT * 4;
    float* proj_rest = (float*)ws;                       // 27.3 MB
    ws += (size_t)T_LEN * B_SZ * NRESTP * 4;
    __hip_bfloat16* attn_bf = (__hip_bfloat16*)ws;       // 4.2 MB
    ws += (size_t)T_LEN * B_SZ * H_N * DH_N * 2;
    __hip_bfloat16* Wp_bf = (__hip_bfloat16*)ws;         // 1 MB
    ws += (size_t)DMODEL * H_N * DH_N * 2;
    _Float16* Wch = (_Float16*)ws;                       // 2.23 MB
    ws += (size_t)NCRIT * DMODEL * 2;
    _Float16* Wcl = (_Float16*)ws;                       // 2.23 MB
    ws += (size_t)NCRIT * DMODEL * 2;
    float* bias_rest = (float*)ws;                       // 6.7 KB
    ws += (size_t)NRESTP * 4;
    char* uni = ws;
    _Float16* Xh      = (_Float16*)uni;
    _Float16* Xl      = (_Float16*)(uni + (size_t)T_LEN * B_SZ * DMODEL * 2);
    _Float16* Wrest_h = (_Float16*)(uni + (size_t)T_LEN * B_SZ * DMODEL * 4);
    float* SPk  = (float*)uni;
    float* SPv4 = (float*)(uni + (size_t)B_SZ * CH * 512 * 24 * 4);
    float* SPv1 = (float*)(uni + (size_t)B_SZ * CH * 512 * 28 * 4);

    // 0) all conversions, one launch
    cvt_fused<<<5312, 256, 0, stream>>>(
        inputs, Wf, bf, Wp, Xh, Xl, Wch, Wcl, Wrest_h, bias_rest, Wp_bf);

    // 1) projection GEMMs, fused launch; col-outer per-XCD swizzle; padded LDS (no bank conflicts)
    gemm_proj<<<NB_CRIT + NB_REST, 256, 0, stream>>>(
        Xh, Xl, Wch, Wcl, Wrest_h, bf, bias_rest, proj_crit, proj_rest);

    // 2) parallel scan (passA feature-split: 1024 blocks of 256 threads)
    scan_passA<<<dim3(B_SZ, CH, 2), dim3(256), 0, stream>>>(
        proj_crit, proj_rest, term, tick, SPk, SPv4, SPv1);
    scan_passB<<<dim3(B_SZ, H_N), dim3(64), 0, stream>>>(
        SPk, SPv4, SPv1, fk_prev, fv_prev, fs_prev, tick,
        out_fk, out_fv, out_fs, out_tick);
    scan_passC<<<dim3(B_SZ, CH), dim3(512), 0, stream>>>(
        proj_crit, proj_rest, term, tick, SPk, SPv4, attn_bf);

    // 3) out = attn @ Wp^T + bp
    gemm_out<<<dim3(DMODEL / 128, (T_LEN * B_SZ) / 64), dim3(256), 0, stream>>>(
        attn_bf, Wp_bf, bp, out);
}

// Round 22
// 147.862 us; speedup vs baseline: 2.6134x; 2.6134x over previous
//
#include <hip/hip_runtime.h>
#include <hip/hip_bf16.h>
#include <math.h>

#define T_LEN  128
#define B_SZ   32
#define DMODEL 1024
#define H_N    8
#define DH_N   64
#define FD_N   256
#define R_N    4
#define NCRIT  1088
#define NREST  1568
#define NRESTP 1664
#define EPS_F  1e-6f
#define CH     16
#define CL     8

#define NB_CRIT 1088   // 8 XCD * 17 col * 8 row
#define NB_REST 832    // 8 XCD * 13 col * 8 row

typedef __attribute__((ext_vector_type(8))) short bf16x8;
typedef __attribute__((ext_vector_type(8))) _Float16 f16x8;
typedef __attribute__((ext_vector_type(4))) float f32x4;

#define LO_SCALE 2048.0f
#define W_SCALE  32.0f

__device__ __forceinline__ float sigmoidf_(float x) { return 1.0f / (1.0f + __expf(-x)); }

// crit layout: [k 8x64][q 8x64][p1 8x4][p2 8x4]
__device__ __forceinline__ int map_crit(int j) {
    if (j < 512)  return (j >> 6) * 320 + (j & 63);
    if (j < 1024) { int t = j - 512;  return (t >> 6) * 320 + 64 + (t & 63); }
    if (j < 1056) { int t = j - 1024; return 2560 + (t >> 2) * 12 + (t & 3); }
    { int t = j - 1056; return 2560 + (t >> 2) * 12 + 4 + (t & 3); }
}
__device__ __forceinline__ int map_rest(int j) {
    if (j < 512)  return (j >> 6) * 320 + 128 + (j & 63);
    if (j < 1024) { int t = j - 512;  return (t >> 6) * 320 + 192 + (t & 63); }
    if (j < 1536) { int t = j - 1024; return (t >> 6) * 320 + 256 + (t & 63); }
    { int t = j - 1536; return 2560 + (t >> 2) * 12 + 8 + (t & 3); }
}

// ---------------- fused conversions ----------------
__global__ __launch_bounds__(256) void cvt_fused(
    const float* __restrict__ inputs, const float* __restrict__ Wf,
    const float* __restrict__ bfv, const float* __restrict__ Wp,
    _Float16* __restrict__ Xh, _Float16* __restrict__ Xl,
    _Float16* __restrict__ Wch, _Float16* __restrict__ Wcl,
    _Float16* __restrict__ Wrest_h, float* __restrict__ bias_rest,
    __hip_bfloat16* __restrict__ Wp_bf)
{
    const int bid = blockIdx.x;
    const int tid = threadIdx.x;
    if (bid < 2048) {
        const int n = T_LEN * B_SZ * DMODEL;
        int i = (bid * 256 + tid) * 4;
        const int stride = 2048 * 256 * 4;
        for (; i < n; i += stride) {
            float4 v = *(const float4*)(inputs + i);
            const float a[4] = {v.x, v.y, v.z, v.w};
            #pragma unroll
            for (int c = 0; c < 4; ++c) {
                const _Float16 h = (_Float16)a[c];
                Xh[i + c] = h;
                Xl[i + c] = (_Float16)((a[c] - (float)h) * LO_SCALE);
            }
        }
    } else if (bid < 3136) {
        const int j = bid - 2048;
        const int i = tid * 4;
        _Float16* dh = Wch + (size_t)j * 1024 + i;
        _Float16* dl = Wcl + (size_t)j * 1024 + i;
        float4 v = *(const float4*)(Wf + (size_t)map_crit(j) * 1024 + i);
        const float a[4] = {v.x * W_SCALE, v.y * W_SCALE, v.z * W_SCALE, v.w * W_SCALE};
        #pragma unroll
        for (int c = 0; c < 4; ++c) {
            const _Float16 h = (_Float16)a[c];
            dh[c] = h;
            dl[c] = (_Float16)((a[c] - (float)h) * LO_SCALE);
        }
    } else if (bid < 4800) {
        const int j = bid - 3136;
        const int i = tid * 4;
        _Float16* dst = Wrest_h + (size_t)j * 1024 + i;
        if (j < NREST) {
            const int wr = map_rest(j);
            float4 v = *(const float4*)(Wf + (size_t)wr * 1024 + i);
            dst[0] = (_Float16)v.x; dst[1] = (_Float16)v.y;
            dst[2] = (_Float16)v.z; dst[3] = (_Float16)v.w;
            if (tid == 0) bias_rest[j] = bfv[wr];
        } else {
            dst[0] = dst[1] = dst[2] = dst[3] = (_Float16)0.f;
            if (tid == 0) bias_rest[j] = 0.f;
        }
    } else {
        const int i = ((bid - 4800) * 256 + tid) * 4;
        float4 v = *(const float4*)(Wp + i);
        Wp_bf[i + 0] = __float2bfloat16(v.x);
        Wp_bf[i + 1] = __float2bfloat16(v.y);
        Wp_bf[i + 2] = __float2bfloat16(v.z);
        Wp_bf[i + 3] = __float2bfloat16(v.w);
    }
}

// ---------------- fused projection GEMM: crit | rest, col-outer per-XCD swizzle ----------------
// LDS row stride 72 f16 = 144 B (9x16 B, keeps b128 alignment; 2-way read aliasing is free).
__global__ __launch_bounds__(256) void gemm_proj(
    const _Float16* __restrict__ Xh, const _Float16* __restrict__ Xl,
    const _Float16* __restrict__ Wch, const _Float16* __restrict__ Wcl,
    const _Float16* __restrict__ Wrest_h,
    const float* __restrict__ bfv, const float* __restrict__ bias_rest,
    float* __restrict__ Cc, float* __restrict__ Cr)
{
    __shared__ __align__(16) char smem[36864];

    const int tid  = threadIdx.x;
    const int wave = tid >> 6, lane = tid & 63;
    const int lr = lane & 15;
    const int lk = (lane >> 4) * 8;
    const int lq = (lane >> 4) * 4;

    if (blockIdx.x < NB_CRIT) {
        _Float16 (*Ah)[72] = (_Float16(*)[72])(smem);
        _Float16 (*Al)[72] = (_Float16(*)[72])(smem + 9216);
        _Float16 (*Bh)[72] = (_Float16(*)[72])(smem + 18432);
        _Float16 (*Bl)[72] = (_Float16(*)[72])(smem + 27648);

        const int xcd  = blockIdx.x & 7;
        const int i2   = blockIdx.x >> 3;        // 0..135
        const int col0 = (i2 >> 3) * 64;         // col-tile slow (0..16)
        const int row0 = (xcd * 8 + (i2 & 7)) * 64;  // row-panel fast within XCD

        const int wr = (wave >> 1) * 32;
        const int wc = (wave & 1) * 32;
        const int sr = tid >> 2;
        const int sk = (tid & 3) * 16;

        const _Float16* xh = Xh + (size_t)(row0 + sr) * 1024 + sk;
        const _Float16* xl = Xl + (size_t)(row0 + sr) * 1024 + sk;
        const _Float16* wh = Wch + (size_t)(col0 + sr) * 1024 + sk;
        const _Float16* wl = Wcl + (size_t)(col0 + sr) * 1024 + sk;

        f32x4 accm[2][2] = {};
        f32x4 accc[2][2] = {};

        f16x8 rah0 = *(const f16x8*)(xh), rah1 = *(const f16x8*)(xh + 8);
        f16x8 ral0 = *(const f16x8*)(xl), ral1 = *(const f16x8*)(xl + 8);
        f16x8 rbh0 = *(const f16x8*)(wh), rbh1 = *(const f16x8*)(wh + 8);
        f16x8 rbl0 = *(const f16x8*)(wl), rbl1 = *(const f16x8*)(wl + 8);

        for (int k0 = 0; k0 < 1024; k0 += 64) {
            *(f16x8*)&Ah[sr][sk]     = rah0;
            *(f16x8*)&Ah[sr][sk + 8] = rah1;
            *(f16x8*)&Al[sr][sk]     = ral0;
            *(f16x8*)&Al[sr][sk + 8] = ral1;
            *(f16x8*)&Bh[sr][sk]     = rbh0;
            *(f16x8*)&Bh[sr][sk + 8] = rbh1;
            *(f16x8*)&Bl[sr][sk]     = rbl0;
            *(f16x8*)&Bl[sr][sk + 8] = rbl1;
            __syncthreads();
            if (k0 + 64 < 1024) {
                rah0 = *(const f16x8*)(xh + k0 + 64); rah1 = *(const f16x8*)(xh + k0 + 72);
                ral0 = *(const f16x8*)(xl + k0 + 64); ral1 = *(const f16x8*)(xl + k0 + 72);
                rbh0 = *(const f16x8*)(wh + k0 + 64); rbh1 = *(const f16x8*)(wh + k0 + 72);
                rbl0 = *(const f16x8*)(wl + k0 + 64); rbl1 = *(const f16x8*)(wl + k0 + 72);
            }
            #pragma unroll
            for (int kk0 = 0; kk0 < 64; kk0 += 32) {
                f16x8 ah[2], al[2], bh[2], bl[2];
                #pragma unroll
                for (int i = 0; i < 2; ++i) {
                    ah[i] = *(const f16x8*)&Ah[wr + i*16 + lr][kk0 + lk];
                    al[i] = *(const f16x8*)&Al[wr + i*16 + lr][kk0 + lk];
                }
                #pragma unroll
                for (int j = 0; j < 2; ++j) {
                    bh[j] = *(const f16x8*)&Bh[wc + j*16 + lr][kk0 + lk];
                    bl[j] = *(const f16x8*)&Bl[wc + j*16 + lr][kk0 + lk];
                }
                #pragma unroll
                for (int i = 0; i < 2; ++i)
                    #pragma unroll
                    for (int j = 0; j < 2; ++j) {
                        accm[i][j] = __builtin_amdgcn_mfma_f32_16x16x32_f16(ah[i], bh[j], accm[i][j], 0, 0, 0);
                        accc[i][j] = __builtin_amdgcn_mfma_f32_16x16x32_f16(ah[i], bl[j], accc[i][j], 0, 0, 0);
                        accc[i][j] = __builtin_amdgcn_mfma_f32_16x16x32_f16(al[i], bh[j], accc[i][j], 0, 0, 0);
                    }
            }
            __syncthreads();
        }

        #pragma unroll
        for (int j = 0; j < 2; ++j) {
            const int col = col0 + wc + j*16 + lr;
            const float bs = bfv[map_crit(col)];
            #pragma unroll
            for (int i = 0; i < 2; ++i) {
                const int rowb = row0 + wr + i*16 + lq;
                #pragma unroll
                for (int r = 0; r < 4; ++r) {
                    const float v = (accm[i][j][r] + accc[i][j][r] * (1.0f/LO_SCALE)) * (1.0f/W_SCALE) + bs;
                    Cc[(size_t)(rowb + r) * NCRIT + col] = v;
                }
            }
        }
    } else {
        _Float16 (*As)[72] = (_Float16(*)[72])(smem);
        _Float16 (*Bs)[72] = (_Float16(*)[72])(smem + 9216);

        const int rb   = blockIdx.x - NB_CRIT;
        const int xcd  = rb & 7;
        const int i2   = rb >> 3;                // 0..103
        const int col0 = (i2 >> 3) * 128;        // col-tile slow (0..12)
        const int row0 = (xcd * 8 + (i2 & 7)) * 64;

        const int wr = (wave >> 1) * 32;
        const int wc = (wave & 1) * 64;
        const int sr = tid >> 2;
        const int sk = (tid & 3) * 16;

        const _Float16* aptr  = Xh + (size_t)(row0 + sr) * 1024 + sk;
        const _Float16* bptr0 = Wrest_h + (size_t)(col0 + sr) * 1024 + sk;
        const _Float16* bptr1 = Wrest_h + (size_t)(col0 + 64 + sr) * 1024 + sk;

        f32x4 acc[2][4] = {};

        f16x8 ra0 = *(const f16x8*)(aptr),  ra1 = *(const f16x8*)(aptr + 8);
        f16x8 rb00 = *(const f16x8*)(bptr0), rb01 = *(const f16x8*)(bptr0 + 8);
        f16x8 rb10 = *(const f16x8*)(bptr1), rb11 = *(const f16x8*)(bptr1 + 8);

        for (int k0 = 0; k0 < 1024; k0 += 64) {
            *(f16x8*)&As[sr][sk]          = ra0;
            *(f16x8*)&As[sr][sk + 8]      = ra1;
            *(f16x8*)&Bs[sr][sk]          = rb00;
            *(f16x8*)&Bs[sr][sk + 8]      = rb01;
            *(f16x8*)&Bs[64 + sr][sk]     = rb10;
            *(f16x8*)&Bs[64 + sr][sk + 8] = rb11;
            __syncthreads();
            if (k0 + 64 < 1024) {
                ra0  = *(const f16x8*)(aptr + k0 + 64);  ra1  = *(const f16x8*)(aptr + k0 + 72);
                rb00 = *(const f16x8*)(bptr0 + k0 + 64); rb01 = *(const f16x8*)(bptr0 + k0 + 72);
                rb10 = *(const f16x8*)(bptr1 + k0 + 64); rb11 = *(const f16x8*)(bptr1 + k0 + 72);
            }
            #pragma unroll
            for (int kk0 = 0; kk0 < 64; kk0 += 32) {
                f16x8 af[2], bfr[4];
                #pragma unroll
                for (int i = 0; i < 2; ++i)
                    af[i] = *(const f16x8*)&As[wr + i*16 + lr][kk0 + lk];
                #pragma unroll
                for (int j = 0; j < 4; ++j)
                    bfr[j] = *(const f16x8*)&Bs[wc + j*16 + lr][kk0 + lk];
                #pragma unroll
                for (int i = 0; i < 2; ++i)
                    #pragma unroll
                    for (int j = 0; j < 4; ++j)
                        acc[i][j] = __builtin_amdgcn_mfma_f32_16x16x32_f16(af[i], bfr[j], acc[i][j], 0, 0, 0);
            }
            __syncthreads();
        }

        #pragma unroll
        for (int j = 0; j < 4; ++j) {
            const int col = col0 + wc + j*16 + lr;
            const float bs = bias_rest[col];
            #pragma unroll
            for (int i = 0; i < 2; ++i) {
                const int rowb = row0 + wr + i*16 + lq;
                #pragma unroll
                for (int r = 0; r < 4; ++r)
                    Cr[(size_t)(rowb + r) * NRESTP + col] = acc[i][j][r] + bs;
            }
        }
    }
}

// ---------------- output projection (bf16 MFMA, dbuf) ----------------
__global__ __launch_bounds__(256) void gemm_out(
    const __hip_bfloat16* __restrict__ A, const __hip_bfloat16* __restrict__ Bm,
    const float* __restrict__ bias, float* __restrict__ C)
{
    __shared__ __align__(16) short As[64][40];
    __shared__ __align__(16) short Bs[128][40];

    const int tid  = threadIdx.x;
    const int wave = tid >> 6, lane = tid & 63;
    const int row0 = blockIdx.y * 64;
    const int col0 = blockIdx.x * 128;
    const int K = H_N * DH_N;

    const int wr = (wave >> 1) * 32;
    const int wc = (wave & 1) * 64;
    const int lr = lane & 15;
    const int lk = (lane >> 4) * 8;
    const int lq = (lane >> 4) * 4;

    const int sr = tid >> 2;
    const int sk = (tid & 3) * 8;

    const short* aptr  = (const short*)A + (size_t)(row0 + sr) * K + sk;
    const short* bptr0 = (const short*)Bm + (size_t)(col0 + sr) * K + sk;
    const short* bptr1 = (const short*)Bm + (size_t)(col0 + 64 + sr) * K + sk;

    f32x4 acc[2][4] = {};

    bf16x8 ra  = *(const bf16x8*)(aptr);
    bf16x8 rb0 = *(const bf16x8*)(bptr0);
    bf16x8 rb1 = *(const bf16x8*)(bptr1);

    for (int k0 = 0; k0 < K; k0 += 32) {
        *(bf16x8*)&As[sr][sk]      = ra;
        *(bf16x8*)&Bs[sr][sk]      = rb0;
        *(bf16x8*)&Bs[64 + sr][sk] = rb1;
        __syncthreads();
        if (k0 + 32 < K) {
            ra  = *(const bf16x8*)(aptr + k0 + 32);
            rb0 = *(const bf16x8*)(bptr0 + k0 + 32);
            rb1 = *(const bf16x8*)(bptr1 + k0 + 32);
        }
        bf16x8 af[2], bfr[4];
        #pragma unroll
        for (int i = 0; i < 2; ++i)
            af[i] = *(const bf16x8*)&As[wr + i*16 + lr][lk];
        #pragma unroll
        for (int j = 0; j < 4; ++j)
            bfr[j] = *(const bf16x8*)&Bs[wc + j*16 + lr][lk];
        #pragma unroll
        for (int i = 0; i < 2; ++i)
            #pragma unroll
            for (int j = 0; j < 4; ++j)
                acc[i][j] = __builtin_amdgcn_mfma_f32_16x16x32_bf16(af[i], bfr[j], acc[i][j], 0, 0, 0);
        __syncthreads();
    }

    #pragma unroll
    for (int j = 0; j < 4; ++j) {
        const int col = col0 + wc + j*16 + lr;
        const float bs = bias[col];
        #pragma unroll
        for (int i = 0; i < 2; ++i) {
            const int rowb = row0 + wr + i*16 + lq;
            #pragma unroll
            for (int r = 0; r < 4; ++r)
                C[(size_t)(rowb + r) * DMODEL + col] = acc[i][j][r] + bs;
        }
    }
}

// ============ parallel scan (CH=16, CL=8) ============
// passA: feature-split — grid (B, CH, 2) x 256 threads; block z owns features z*256..z*256+255.
__global__ __launch_bounds__(256, 1)
void scan_passA(const float* __restrict__ pc, const float* __restrict__ pr,
                const int* __restrict__ term, const float* __restrict__ tick_in,
                float* __restrict__ SPk, float* __restrict__ SPv4, float* __restrict__ SPv1)
{
    const int b = blockIdx.x, c = blockIdx.y;
    const int ftid = blockIdx.z * 256 + threadIdx.x;   // 0..511
    const int w = ftid >> 6, lane = ftid & 63;
    const int t0 = c * CL;

    __shared__ __align__(16) float cos_s[CL][4];
    const float tick_b = tick_in[b];
    if (threadIdx.x < CL * 4) {
        const int lt = threadIdx.x >> 2, r = threadIdx.x & 3;
        const float PI_F = 3.14159265358979323846f;
        const float omega[4] = {-PI_F, -PI_F/3.0f, PI_F/3.0f, PI_F};
        cos_s[lt][r] = cosf(((float)(t0 + lt + 1) + tick_b) * omega[r]);
    }
    __syncthreads();

    float Sk[4][4] = {}, Ss[4] = {}, Sv[4] = {};
    float Pd[4] = {1.f, 1.f, 1.f, 1.f};
    float Pv = 1.f;

    float ck, cv, cbt, cg, ctm; float4 cp1, cp3;
    auto loadA = [&](int lt, float& k, float& v, float& bt, float& g,
                     float4& p1, float4& p3, float& tm) {
        const int t = t0 + ((lt < CL) ? lt : CL - 1);
        const float* Pc = pc + (size_t)(t * B_SZ + b) * NCRIT;
        const float* Pr = pr + (size_t)(t * B_SZ + b) * NRESTP;
        k  = Pc[w*64 + lane];
        p1 = *(const float4*)(Pc + 1024 + w*4);
        v  = Pr[w*64 + lane];
        bt = Pr[512 + w*64 + lane];
        g  = Pr[1024 + w*64 + lane];
        p3 = *(const float4*)(Pr + 1536 + w*4);
        tm = (float)term[t * B_SZ + b];
    };
    loadA(0, ck, cv, cbt, cg, cp1, cp3, ctm);

    for (int lt = 0; lt < CL; ++lt) {
        float nk, nv, nbt, ng, ntm; float4 np1, np3;
        loadA(lt + 1, nk, nv, nbt, ng, np1, np3, ntm);

        const float mask = 1.f - ctm;
        const float4 cs4 = *(const float4*)&cos_s[lt][0];
        const float cosr[4] = {cs4.x, cs4.y, cs4.z, cs4.w};
        const float rk = fmaxf(ck, 0.f);
        const float sg = sigmoidf_(cg);
        const float p1v[4] = {cp1.x, cp1.y, cp1.z, cp1.w};
        const float p3v[4] = {cp3.x, cp3.y, cp3.z, cp3.w};

        #pragma unroll
        for (int e = 0; e < 4; ++e) {
            const float psi = rk * fmaxf(p1v[e], 0.f);
            const float gf  = sg * sigmoidf_(p3v[e]);
            const float kg  = psi * gf;
            const float dg  = (1.f - gf) * mask;
            #pragma unroll
            for (int r = 0; r < 4; ++r)
                Sk[r][e] = dg * Sk[r][e] + kg * cosr[r];
            Ss[e] = dg * Ss[e] + kg;
            Pd[e] *= dg;
        }
        const float bb = sigmoidf_(cbt);
        const float vg = cv * bb;
        const float db = (1.f - bb) * mask;
        #pragma unroll
        for (int r = 0; r < 4; ++r) Sv[r] = db * Sv[r] + vg * cosr[r];
        Pv *= db;

        ck = nk; cv = nv; cbt = nbt; cg = ng; cp1 = np1; cp3 = np3; ctm = ntm;
    }

    float* K = SPk + ((size_t)(b * CH + c) * 512 + ftid) * 24;
    #pragma unroll
    for (int r = 0; r < 4; ++r)
        *(float4*)(K + r*4) = make_float4(Sk[r][0], Sk[r][1], Sk[r][2], Sk[r][3]);
    *(float4*)(K + 16) = make_float4(Pd[0], Pd[1], Pd[2], Pd[3]);
    *(float4*)(K + 20) = make_float4(Ss[0], Ss[1], Ss[2], Ss[3]);
    *(float4*)(SPv4 + ((size_t)(b * CH + c) * 512 + ftid) * 4) =
        make_float4(Sv[0], Sv[1], Sv[2], Sv[3]);
    SPv1[(size_t)(b * CH + c) * 512 + ftid] = Pv;
}

// passB: feature-parallel carry combine (256 blocks, reg-prefetch)
__global__ __launch_bounds__(64, 4)
void scan_passB(float* __restrict__ SPk, float* __restrict__ SPv4,
                const float* __restrict__ SPv1,
                const float* __restrict__ fk_prev, const float* __restrict__ fv_prev,
                const float* __restrict__ fs_prev, const float* __restrict__ tick_in,
                float* __restrict__ out_fk, float* __restrict__ out_fv,
                float* __restrict__ out_fs, float* __restrict__ out_tick)
{
    const int b = blockIdx.x, w = blockIdx.y;
    const int lane = threadIdx.x;
    const int ftid = w * 64 + lane;
    const int f0 = lane << 2;

    float yk[4][4], ys[4], yv[4];
    #pragma unroll
    for (int r = 0; r < 4; ++r) {
        const float4 kk = *(const float4*)(fk_prev + (((size_t)b * R_N + r) * H_N + w) * FD_N + f0);
        yk[r][0] = kk.x; yk[r][1] = kk.y; yk[r][2] = kk.z; yk[r][3] = kk.w;
        yv[r] = fv_prev[(((size_t)b * R_N + r) * H_N + w) * DH_N + lane];
    }
    {
        const float4 ss = *(const float4*)(fs_prev + ((size_t)b * H_N + w) * FD_N + f0);
        ys[0] = ss.x; ys[1] = ss.y; ys[2] = ss.z; ys[3] = ss.w;
    }

    const size_t stride = (size_t)512 * 24;
    const size_t strideV = (size_t)512 * 4;
    float* K0 = SPk + ((size_t)(b * CH) * 512 + ftid) * 24;
    float* V0 = SPv4 + ((size_t)(b * CH) * 512 + ftid) * 4;
    const float* P0 = SPv1 + (size_t)(b * CH) * 512 + ftid;

    float4 S0 = *(float4*)(K0 + 0),  S1 = *(float4*)(K0 + 4);
    float4 S2 = *(float4*)(K0 + 8),  S3 = *(float4*)(K0 + 12);
    float4 P4 = *(float4*)(K0 + 16), Q4 = *(float4*)(K0 + 20);
    float4 Sv4 = *(float4*)V0;
    float  Pv  = P0[0];

    for (int c = 0; c < CH; ++c) {
        float* K = K0 + (size_t)c * stride;
        float* V = V0 + (size_t)c * strideV;

        const float4 cS0 = S0, cS1 = S1, cS2 = S2, cS3 = S3, cP4 = P4, cQ4 = Q4, cSv = Sv4;
        const float cPv = Pv;

        if (c + 1 < CH) {
            float* Kn = K0 + (size_t)(c + 1) * stride;
            float* Vn = V0 + (size_t)(c + 1) * strideV;
            S0 = *(float4*)(Kn + 0);  S1 = *(float4*)(Kn + 4);
            S2 = *(float4*)(Kn + 8);  S3 = *(float4*)(Kn + 12);
            P4 = *(float4*)(Kn + 16); Q4 = *(float4*)(Kn + 20);
            Sv4 = *(float4*)Vn;
            Pv  = P0[(size_t)(c + 1) * 512];
        }

        *(float4*)(K + 0)  = make_float4(yk[0][0], yk[0][1], yk[0][2], yk[0][3]);
        *(float4*)(K + 4)  = make_float4(yk[1][0], yk[1][1], yk[1][2], yk[1][3]);
        *(float4*)(K + 8)  = make_float4(yk[2][0], yk[2][1], yk[2][2], yk[2][3]);
        *(float4*)(K + 12) = make_float4(yk[3][0], yk[3][1], yk[3][2], yk[3][3]);
        *(float4*)(K + 20) = make_float4(ys[0], ys[1], ys[2], ys[3]);
        *(float4*)V        = make_float4(yv[0], yv[1], yv[2], yv[3]);

        const float S[4][4] = {{cS0.x,cS0.y,cS0.z,cS0.w}, {cS1.x,cS1.y,cS1.z,cS1.w},
                               {cS2.x,cS2.y,cS2.z,cS2.w}, {cS3.x,cS3.y,cS3.z,cS3.w}};
        const float Pd[4] = {cP4.x, cP4.y, cP4.z, cP4.w};
        const float Ssv[4] = {cQ4.x, cQ4.y, cQ4.z, cQ4.w};
        const float Svv[4] = {cSv.x, cSv.y, cSv.z, cSv.w};
        #pragma unroll
        for (int e = 0; e < 4; ++e) {
            #pragma unroll
            for (int r = 0; r < 4; ++r)
                yk[r][e] = S[r][e] + Pd[e] * yk[r][e];
            ys[e] = Ssv[e] + Pd[e] * ys[e];
        }
        #pragma unroll
        for (int r = 0; r < 4; ++r)
            yv[r] = Svv[r] + cPv * yv[r];
    }

    #pragma unroll
    for (int r = 0; r < 4; ++r) {
        *(float4*)(out_fk + (((size_t)b * R_N + r) * H_N + w) * FD_N + f0) =
            make_float4(yk[r][0], yk[r][1], yk[r][2], yk[r][3]);
        out_fv[(((size_t)b * R_N + r) * H_N + w) * DH_N + lane] = yv[r];
    }
    *(float4*)(out_fs + ((size_t)b * H_N + w) * FD_N + f0) =
        make_float4(ys[0], ys[1], ys[2], ys[3]);
    if (w == 0 && lane == 0) out_tick[b] = tick_in[b] + (float)T_LEN;
}

struct PF {
    float k[4], q[4], v[4], bt[4], g[4], tm[4];
    float4 p1[4], p2[4], p3[4];
};

__global__ __launch_bounds__(512, 1)
void scan_passC(const float* __restrict__ pc, const float* __restrict__ pr,
                const int* __restrict__ term, const float* __restrict__ tick_in,
                const float* __restrict__ SPk, const float* __restrict__ SPv4,
                __hip_bfloat16* __restrict__ attn)
{
    const int b = blockIdx.x, c = blockIdx.y;
    const int tid = threadIdx.x, w = tid >> 6, lane = tid & 63;
    const int tc0 = c * CL;

    __shared__ float red[2][4][8][4];
    __shared__ __align__(16) float cos_s[CL][4];

    const float tick_b = tick_in[b];
    if (tid < CL * 4) {
        const int lt = tid >> 2, r = tid & 3;
        const float PI_F = 3.14159265358979323846f;
        const float omega[4] = {-PI_F, -PI_F/3.0f, PI_F/3.0f, PI_F};
        cos_s[lt][r] = cosf(((float)(tc0 + lt + 1) + tick_b) * omega[r]);
    }

    float fk[4][4], fsv[4], fv[4];
    {
        const float* K = SPk + ((size_t)(b * CH + c) * 512 + tid) * 24;
        #pragma unroll
        for (int r = 0; r < 4; ++r) {
            const float4 kk = *(const float4*)(K + r*4);
            fk[r][0] = kk.x; fk[r][1] = kk.y; fk[r][2] = kk.z; fk[r][3] = kk.w;
        }
        const float4 s4 = *(const float4*)(K + 20);
        fsv[0] = s4.x; fsv[1] = s4.y; fsv[2] = s4.z; fsv[3] = s4.w;
        const float4 v4 = *(const float4*)(SPv4 + ((size_t)(b * CH + c) * 512 + tid) * 4);
        fv[0] = v4.x; fv[1] = v4.y; fv[2] = v4.z; fv[3] = v4.w;
    }

    auto prefetch = [&](PF& dst, int lt0) {
        #pragma unroll
        for (int s = 0; s < 4; ++s) {
            int lt = lt0 + s; lt = (lt < CL) ? lt : CL - 1;
            const int t = tc0 + lt;
            const float* Pc = pc + (size_t)(t * B_SZ + b) * NCRIT;
            const float* Pr = pr + (size_t)(t * B_SZ + b) * NRESTP;
            dst.k[s]  = Pc[w*64 + lane];
            dst.q[s]  = Pc[512 + w*64 + lane];
            dst.p1[s] = *(const float4*)(Pc + 1024 + w*4);
            dst.p2[s] = *(const float4*)(Pc + 1056 + w*4);
            dst.v[s]  = Pr[w*64 + lane];
            dst.bt[s] = Pr[512 + w*64 + lane];
            dst.g[s]  = Pr[1024 + w*64 + lane];
            dst.p3[s] = *(const float4*)(Pr + 1536 + w*4);
            dst.tm[s] = (float)term[t * B_SZ + b];
        }
    };

    auto round_body = [&](const PF& cur, int lt0, int P) {
        float sc[4][4], nr[4], fvs[4][4];
        #pragma unroll
        for (int s = 0; s < 4; ++s) {
            const float mask = 1.f - cur.tm[s];
            const float4 cs = *(const float4*)&cos_s[lt0 + s][0];
            const float cosr[4] = {cs.x, cs.y, cs.z, cs.w};
            const float rk = fmaxf(cur.k[s], 0.f);
            const float rq = fmaxf(cur.q[s], 0.f);
            const float sg = sigmoidf_(cur.g[s]);
            const float p1v[4] = {cur.p1[s].x, cur.p1[s].y, cur.p1[s].z, cur.p1[s].w};
            const float p2v[4] = {cur.p2[s].x, cur.p2[s].y, cur.p2[s].z, cur.p2[s].w};
            const float p3v[4] = {cur.p3[s].x, cur.p3[s].y, cur.p3[s].z, cur.p3[s].w};
            float phi[4], kg[4], dgv[4];
            float np = 0.f;
            #pragma unroll
            for (int e = 0; e < 4; ++e) {
                const float psi = rk * fmaxf(p1v[e], 0.f);
                phi[e] = rq * fmaxf(p2v[e], 0.f);
                const float gf = sg * sigmoidf_(p3v[e]);
                kg[e] = psi * gf;
                dgv[e] = (1.f - gf) * mask;
                fsv[e] = dgv[e] * fsv[e] + kg[e];
                np += fsv[e] * phi[e];
            }
            nr[s] = np;
            #pragma unroll
            for (int r = 0; r < R_N; ++r) {
                float ss = 0.f;
                #pragma unroll
                for (int e = 0; e < 4; ++e) {
                    fk[r][e] = dgv[e] * fk[r][e] + kg[e] * cosr[r];
                    ss += fk[r][e] * phi[e];
                }
                sc[s][r] = ss;
            }
            const float bb = sigmoidf_(cur.bt[s]);
            const float vg = cur.v[s] * bb;
            const float db = (1.f - bb) * mask;
            #pragma unroll
            for (int r = 0; r < R_N; ++r) { fv[r] = db * fv[r] + vg * cosr[r]; fvs[s][r] = fv[r]; }
        }
        #pragma unroll
        for (int off = 32; off >= 1; off >>= 1) {
            #pragma unroll
            for (int s = 0; s < 4; ++s) {
                #pragma unroll
                for (int r = 0; r < 4; ++r) sc[s][r] += __shfl_xor(sc[s][r], off);
                nr[s] += __shfl_xor(nr[s], off);
            }
        }
        if (lane == 0) {
            #pragma unroll
            for (int s = 0; s < 4; ++s)
                *(float4*)&red[P][s][w][0] = make_float4(sc[s][0], sc[s][1], sc[s][2], sc[s][3]);
        }
        __syncthreads();
        #pragma unroll
        for (int s = 0; s < 4; ++s) {
            float s0 = 0.f, s1 = 0.f, s2 = 0.f, s3 = 0.f;
            #pragma unroll
            for (int ww = 0; ww < 8; ++ww) {
                const float4 rv = *(const float4*)&red[P][s][ww][0];
                s0 += rv.x; s1 += rv.y; s2 += rv.z; s3 += rv.w;
            }
            const float kv = fvs[s][0]*s0 + fvs[s][1]*s1 + fvs[s][2]*s2 + fvs[s][3]*s3;
            attn[((size_t)(tc0 + lt0 + s) * B_SZ + b) * (H_N * DH_N) + tid] =
                __float2bfloat16(kv / (2.0f * R_N * nr[s] + EPS_F));
        }
    };

    PF Abuf, Bbuf;
    prefetch(Abuf, 0);
    __syncthreads();

    for (int lt0 = 0; lt0 < CL; lt0 += 8) {
        prefetch(Bbuf, lt0 + 4);
        round_body(Abuf, lt0, 0);
        prefetch(Abuf, lt0 + 8);
        round_body(Bbuf, lt0 + 4, 1);
    }
}

extern "C" void kernel_launch(void* const* d_in, const int* in_sizes, int n_in,
                              void* d_out, int out_size, void* d_ws, size_t ws_size,
                              hipStream_t stream)
{
    const float* inputs  = (const float*)d_in[0];
    const int*   term    = (const int*)  d_in[1];
    const float* fk_prev = (const float*)d_in[2];
    const float* fv_prev = (const float*)d_in[3];
    const float* fs_prev = (const float*)d_in[4];
    const float* tick    = (const float*)d_in[5];
    const float* Wf      = (const float*)d_in[6];
    const float* bf      = (const float*)d_in[7];
    const float* Wp      = (const float*)d_in[8];
    const float* bp      = (const float*)d_in[9];

    float* out      = (float*)d_out;
    float* out_fk   = out    + (size_t)T_LEN * B_SZ * DMODEL;
    float* out_fv   = out_fk + (size_t)B_SZ * R_N * H_N * FD_N;
    float* out_fs   = out_fv + (size_t)B_SZ * R_N * H_N * DH_N;
    float* out_tick = out_fs + (size_t)B_SZ * H_N * FD_N;

    char* ws = (char*)d_ws;
    float* proj_crit = (float*)ws;                       // 17.8 MB
    ws += (size_t)T_LEN * B_SZ * NCRIT * 4;
    float* proj_rest = (float*)ws;                       // 27.3 MB
    ws += (size_t)T_LEN * B_SZ * NRESTP * 4;
    __hip_bfloat16* attn_bf = (__hip_bfloat16*)ws;       // 4.2 MB
    ws += (size_t)T_LEN * B_SZ * H_N * DH_N * 2;
    __hip_bfloat16* Wp_bf = (__hip_bfloat16*)ws;         // 1 MB
    ws += (size_t)DMODEL * H_N * DH_N * 2;
    _Float16* Wch = (_Float16*)ws;                       // 2.23 MB
    ws += (size_t)NCRIT * DMODEL * 2;
    _Float16* Wcl = (_Float16*)ws;                       // 2.23 MB
    ws += (size_t)NCRIT * DMODEL * 2;
    float* bias_rest = (float*)ws;                       // 6.7 KB
    ws += (size_t)NRESTP * 4;
    char* uni = ws;
    _Float16* Xh      = (_Float16*)uni;
    _Float16* Xl      = (_Float16*)(uni + (size_t)T_LEN * B_SZ * DMODEL * 2);
    _Float16* Wrest_h = (_Float16*)(uni + (size_t)T_LEN * B_SZ * DMODEL * 4);
    float* SPk  = (float*)uni;
    float* SPv4 = (float*)(uni + (size_t)B_SZ * CH * 512 * 24 * 4);
    float* SPv1 = (float*)(uni + (size_t)B_SZ * CH * 512 * 28 * 4);

    // 0) all conversions, one launch
    cvt_fused<<<5312, 256, 0, stream>>>(
        inputs, Wf, bf, Wp, Xh, Xl, Wch, Wcl, Wrest_h, bias_rest, Wp_bf);

    // 1) projection GEMMs, fused launch; col-outer per-XCD swizzle; stride-72 LDS (aligned)
    gemm_proj<<<NB_CRIT + NB_REST, 256, 0, stream>>>(
        Xh, Xl, Wch, Wcl, Wrest_h, bf, bias_rest, proj_crit, proj_rest);

    // 2) parallel scan (passA feature-split: 1024 blocks of 256 threads)
    scan_passA<<<dim3(B_SZ, CH, 2), dim3(256), 0, stream>>>(
        proj_crit, proj_rest, term, tick, SPk, SPv4, SPv1);
    scan_passB<<<dim3(B_SZ, H_N), dim3(64), 0, stream>>>(
        SPk, SPv4, SPv1, fk_prev, fv_prev, fs_prev, tick,
        out_fk, out_fv, out_fs, out_tick);
    scan_passC<<<dim3(B_SZ, CH), dim3(512), 0, stream>>>(
        proj_crit, proj_rest, term, tick, SPk, SPv4, attn_bf);

    // 3) out = attn @ Wp^T + bp
    gemm_out<<<dim3(DMODEL / 128, (T_LEN * B_SZ) / 64), dim3(256), 0, stream>>>(
        attn_bf, Wp_bf, bp, out);
}

// Round 23
// 147.254 us; speedup vs baseline: 2.6242x; 1.0041x over previous
//
#include <hip/hip_runtime.h>
#include <hip/hip_bf16.h>
#include <math.h>

#define T_LEN  128
#define B_SZ   32
#define DMODEL 1024
#define H_N    8
#define DH_N   64
#define FD_N   256
#define R_N    4
#define NCRIT  1088
#define NREST  1568
#define NRESTP 1664
#define EPS_F  1e-6f
#define CH     16
#define CL     8

#define NB_CRIT 1088   // 8 XCD * 17 col * 8 row
#define NB_REST 832    // 8 XCD * 13 col * 8 row

typedef __attribute__((ext_vector_type(8))) short bf16x8;
typedef __attribute__((ext_vector_type(8))) _Float16 f16x8;
typedef __attribute__((ext_vector_type(4))) float f32x4;

#define LO_SCALE 2048.0f
#define W_SCALE  32.0f

__device__ __forceinline__ float sigmoidf_(float x) { return 1.0f / (1.0f + __expf(-x)); }

// crit layout: [k 8x64][q 8x64][p1 8x4][p2 8x4]
__device__ __forceinline__ int map_crit(int j) {
    if (j < 512)  return (j >> 6) * 320 + (j & 63);
    if (j < 1024) { int t = j - 512;  return (t >> 6) * 320 + 64 + (t & 63); }
    if (j < 1056) { int t = j - 1024; return 2560 + (t >> 2) * 12 + (t & 3); }
    { int t = j - 1056; return 2560 + (t >> 2) * 12 + 4 + (t & 3); }
}
__device__ __forceinline__ int map_rest(int j) {
    if (j < 512)  return (j >> 6) * 320 + 128 + (j & 63);
    if (j < 1024) { int t = j - 512;  return (t >> 6) * 320 + 192 + (t & 63); }
    if (j < 1536) { int t = j - 1024; return (t >> 6) * 320 + 256 + (t & 63); }
    { int t = j - 1536; return 2560 + (t >> 2) * 12 + 8 + (t & 3); }
}

// ---------------- fused conversions ----------------
__global__ __launch_bounds__(256) void cvt_fused(
    const float* __restrict__ inputs, const float* __restrict__ Wf,
    const float* __restrict__ bfv, const float* __restrict__ Wp,
    _Float16* __restrict__ Xh, _Float16* __restrict__ Xl,
    _Float16* __restrict__ Wch, _Float16* __restrict__ Wcl,
    _Float16* __restrict__ Wrest_h, float* __restrict__ bias_rest,
    __hip_bfloat16* __restrict__ Wp_bf)
{
    const int bid = blockIdx.x;
    const int tid = threadIdx.x;
    if (bid < 2048) {
        const int n = T_LEN * B_SZ * DMODEL;
        int i = (bid * 256 + tid) * 4;
        const int stride = 2048 * 256 * 4;
        for (; i < n; i += stride) {
            float4 v = *(const float4*)(inputs + i);
            const float a[4] = {v.x, v.y, v.z, v.w};
            #pragma unroll
            for (int c = 0; c < 4; ++c) {
                const _Float16 h = (_Float16)a[c];
                Xh[i + c] = h;
                Xl[i + c] = (_Float16)((a[c] - (float)h) * LO_SCALE);
            }
        }
    } else if (bid < 3136) {
        const int j = bid - 2048;
        const int i = tid * 4;
        _Float16* dh = Wch + (size_t)j * 1024 + i;
        _Float16* dl = Wcl + (size_t)j * 1024 + i;
        float4 v = *(const float4*)(Wf + (size_t)map_crit(j) * 1024 + i);
        const float a[4] = {v.x * W_SCALE, v.y * W_SCALE, v.z * W_SCALE, v.w * W_SCALE};
        #pragma unroll
        for (int c = 0; c < 4; ++c) {
            const _Float16 h = (_Float16)a[c];
            dh[c] = h;
            dl[c] = (_Float16)((a[c] - (float)h) * LO_SCALE);
        }
    } else if (bid < 4800) {
        const int j = bid - 3136;
        const int i = tid * 4;
        _Float16* dst = Wrest_h + (size_t)j * 1024 + i;
        if (j < NREST) {
            const int wr = map_rest(j);
            float4 v = *(const float4*)(Wf + (size_t)wr * 1024 + i);
            dst[0] = (_Float16)v.x; dst[1] = (_Float16)v.y;
            dst[2] = (_Float16)v.z; dst[3] = (_Float16)v.w;
            if (tid == 0) bias_rest[j] = bfv[wr];
        } else {
            dst[0] = dst[1] = dst[2] = dst[3] = (_Float16)0.f;
            if (tid == 0) bias_rest[j] = 0.f;
        }
    } else {
        const int i = ((bid - 4800) * 256 + tid) * 4;
        float4 v = *(const float4*)(Wp + i);
        Wp_bf[i + 0] = __float2bfloat16(v.x);
        Wp_bf[i + 1] = __float2bfloat16(v.y);
        Wp_bf[i + 2] = __float2bfloat16(v.z);
        Wp_bf[i + 3] = __float2bfloat16(v.w);
    }
}

// ---------------- fused projection GEMM: crit | rest, col-outer per-XCD swizzle ----------------
// LDS row stride 72 f16 = 144 B (9x16 B: keeps b128 alignment). launch_bounds(256,4):
// request 4 blocks/CU residency (LDS 36.9KB x4 = 147KB < 160KB; VGPR cap 128 > 72 used).
__global__ __launch_bounds__(256, 4) void gemm_proj(
    const _Float16* __restrict__ Xh, const _Float16* __restrict__ Xl,
    const _Float16* __restrict__ Wch, const _Float16* __restrict__ Wcl,
    const _Float16* __restrict__ Wrest_h,
    const float* __restrict__ bfv, const float* __restrict__ bias_rest,
    float* __restrict__ Cc, float* __restrict__ Cr)
{
    __shared__ __align__(16) char smem[36864];

    const int tid  = threadIdx.x;
    const int wave = tid >> 6, lane = tid & 63;
    const int lr = lane & 15;
    const int lk = (lane >> 4) * 8;
    const int lq = (lane >> 4) * 4;

    if (blockIdx.x < NB_CRIT) {
        _Float16 (*Ah)[72] = (_Float16(*)[72])(smem);
        _Float16 (*Al)[72] = (_Float16(*)[72])(smem + 9216);
        _Float16 (*Bh)[72] = (_Float16(*)[72])(smem + 18432);
        _Float16 (*Bl)[72] = (_Float16(*)[72])(smem + 27648);

        const int xcd  = blockIdx.x & 7;
        const int i2   = blockIdx.x >> 3;        // 0..135
        const int col0 = (i2 >> 3) * 64;         // col-tile slow (0..16)
        const int row0 = (xcd * 8 + (i2 & 7)) * 64;  // row-panel fast within XCD

        const int wr = (wave >> 1) * 32;
        const int wc = (wave & 1) * 32;
        const int sr = tid >> 2;
        const int sk = (tid & 3) * 16;

        const _Float16* xh = Xh + (size_t)(row0 + sr) * 1024 + sk;
        const _Float16* xl = Xl + (size_t)(row0 + sr) * 1024 + sk;
        const _Float16* wh = Wch + (size_t)(col0 + sr) * 1024 + sk;
        const _Float16* wl = Wcl + (size_t)(col0 + sr) * 1024 + sk;

        f32x4 accm[2][2] = {};
        f32x4 accc[2][2] = {};

        f16x8 rah0 = *(const f16x8*)(xh), rah1 = *(const f16x8*)(xh + 8);
        f16x8 ral0 = *(const f16x8*)(xl), ral1 = *(const f16x8*)(xl + 8);
        f16x8 rbh0 = *(const f16x8*)(wh), rbh1 = *(const f16x8*)(wh + 8);
        f16x8 rbl0 = *(const f16x8*)(wl), rbl1 = *(const f16x8*)(wl + 8);

        for (int k0 = 0; k0 < 1024; k0 += 64) {
            *(f16x8*)&Ah[sr][sk]     = rah0;
            *(f16x8*)&Ah[sr][sk + 8] = rah1;
            *(f16x8*)&Al[sr][sk]     = ral0;
            *(f16x8*)&Al[sr][sk + 8] = ral1;
            *(f16x8*)&Bh[sr][sk]     = rbh0;
            *(f16x8*)&Bh[sr][sk + 8] = rbh1;
            *(f16x8*)&Bl[sr][sk]     = rbl0;
            *(f16x8*)&Bl[sr][sk + 8] = rbl1;
            __syncthreads();
            if (k0 + 64 < 1024) {
                rah0 = *(const f16x8*)(xh + k0 + 64); rah1 = *(const f16x8*)(xh + k0 + 72);
                ral0 = *(const f16x8*)(xl + k0 + 64); ral1 = *(const f16x8*)(xl + k0 + 72);
                rbh0 = *(const f16x8*)(wh + k0 + 64); rbh1 = *(const f16x8*)(wh + k0 + 72);
                rbl0 = *(const f16x8*)(wl + k0 + 64); rbl1 = *(const f16x8*)(wl + k0 + 72);
            }
            #pragma unroll
            for (int kk0 = 0; kk0 < 64; kk0 += 32) {
                f16x8 ah[2], al[2], bh[2], bl[2];
                #pragma unroll
                for (int i = 0; i < 2; ++i) {
                    ah[i] = *(const f16x8*)&Ah[wr + i*16 + lr][kk0 + lk];
                    al[i] = *(const f16x8*)&Al[wr + i*16 + lr][kk0 + lk];
                }
                #pragma unroll
                for (int j = 0; j < 2; ++j) {
                    bh[j] = *(const f16x8*)&Bh[wc + j*16 + lr][kk0 + lk];
                    bl[j] = *(const f16x8*)&Bl[wc + j*16 + lr][kk0 + lk];
                }
                #pragma unroll
                for (int i = 0; i < 2; ++i)
                    #pragma unroll
                    for (int j = 0; j < 2; ++j) {
                        accm[i][j] = __builtin_amdgcn_mfma_f32_16x16x32_f16(ah[i], bh[j], accm[i][j], 0, 0, 0);
                        accc[i][j] = __builtin_amdgcn_mfma_f32_16x16x32_f16(ah[i], bl[j], accc[i][j], 0, 0, 0);
                        accc[i][j] = __builtin_amdgcn_mfma_f32_16x16x32_f16(al[i], bh[j], accc[i][j], 0, 0, 0);
                    }
            }
            __syncthreads();
        }

        #pragma unroll
        for (int j = 0; j < 2; ++j) {
            const int col = col0 + wc + j*16 + lr;
            const float bs = bfv[map_crit(col)];
            #pragma unroll
            for (int i = 0; i < 2; ++i) {
                const int rowb = row0 + wr + i*16 + lq;
                #pragma unroll
                for (int r = 0; r < 4; ++r) {
                    const float v = (accm[i][j][r] + accc[i][j][r] * (1.0f/LO_SCALE)) * (1.0f/W_SCALE) + bs;
                    Cc[(size_t)(rowb + r) * NCRIT + col] = v;
                }
            }
        }
    } else {
        _Float16 (*As)[72] = (_Float16(*)[72])(smem);
        _Float16 (*Bs)[72] = (_Float16(*)[72])(smem + 9216);

        const int rb   = blockIdx.x - NB_CRIT;
        const int xcd  = rb & 7;
        const int i2   = rb >> 3;                // 0..103
        const int col0 = (i2 >> 3) * 128;        // col-tile slow (0..12)
        const int row0 = (xcd * 8 + (i2 & 7)) * 64;

        const int wr = (wave >> 1) * 32;
        const int wc = (wave & 1) * 64;
        const int sr = tid >> 2;
        const int sk = (tid & 3) * 16;

        const _Float16* aptr  = Xh + (size_t)(row0 + sr) * 1024 + sk;
        const _Float16* bptr0 = Wrest_h + (size_t)(col0 + sr) * 1024 + sk;
        const _Float16* bptr1 = Wrest_h + (size_t)(col0 + 64 + sr) * 1024 + sk;

        f32x4 acc[2][4] = {};

        f16x8 ra0 = *(const f16x8*)(aptr),  ra1 = *(const f16x8*)(aptr + 8);
        f16x8 rb00 = *(const f16x8*)(bptr0), rb01 = *(const f16x8*)(bptr0 + 8);
        f16x8 rb10 = *(const f16x8*)(bptr1), rb11 = *(const f16x8*)(bptr1 + 8);

        for (int k0 = 0; k0 < 1024; k0 += 64) {
            *(f16x8*)&As[sr][sk]          = ra0;
            *(f16x8*)&As[sr][sk + 8]      = ra1;
            *(f16x8*)&Bs[sr][sk]          = rb00;
            *(f16x8*)&Bs[sr][sk + 8]      = rb01;
            *(f16x8*)&Bs[64 + sr][sk]     = rb10;
            *(f16x8*)&Bs[64 + sr][sk + 8] = rb11;
            __syncthreads();
            if (k0 + 64 < 1024) {
                ra0  = *(const f16x8*)(aptr + k0 + 64);  ra1  = *(const f16x8*)(aptr + k0 + 72);
                rb00 = *(const f16x8*)(bptr0 + k0 + 64); rb01 = *(const f16x8*)(bptr0 + k0 + 72);
                rb10 = *(const f16x8*)(bptr1 + k0 + 64); rb11 = *(const f16x8*)(bptr1 + k0 + 72);
            }
            #pragma unroll
            for (int kk0 = 0; kk0 < 64; kk0 += 32) {
                f16x8 af[2], bfr[4];
                #pragma unroll
                for (int i = 0; i < 2; ++i)
                    af[i] = *(const f16x8*)&As[wr + i*16 + lr][kk0 + lk];
                #pragma unroll
                for (int j = 0; j < 4; ++j)
                    bfr[j] = *(const f16x8*)&Bs[wc + j*16 + lr][kk0 + lk];
                #pragma unroll
                for (int i = 0; i < 2; ++i)
                    #pragma unroll
                    for (int j = 0; j < 4; ++j)
                        acc[i][j] = __builtin_amdgcn_mfma_f32_16x16x32_f16(af[i], bfr[j], acc[i][j], 0, 0, 0);
            }
            __syncthreads();
        }

        #pragma unroll
        for (int j = 0; j < 4; ++j) {
            const int col = col0 + wc + j*16 + lr;
            const float bs = bias_rest[col];
            #pragma unroll
            for (int i = 0; i < 2; ++i) {
                const int rowb = row0 + wr + i*16 + lq;
                #pragma unroll
                for (int r = 0; r < 4; ++r)
                    Cr[(size_t)(rowb + r) * NRESTP + col] = acc[i][j][r] + bs;
            }
        }
    }
}

// ---------------- output projection (bf16 MFMA, dbuf) ----------------
__global__ __launch_bounds__(256) void gemm_out(
    const __hip_bfloat16* __restrict__ A, const __hip_bfloat16* __restrict__ Bm,
    const float* __restrict__ bias, float* __restrict__ C)
{
    __shared__ __align__(16) short As[64][40];
    __shared__ __align__(16) short Bs[128][40];

    const int tid  = threadIdx.x;
    const int wave = tid >> 6, lane = tid & 63;
    const int row0 = blockIdx.y * 64;
    const int col0 = blockIdx.x * 128;
    const int K = H_N * DH_N;

    const int wr = (wave >> 1) * 32;
    const int wc = (wave & 1) * 64;
    const int lr = lane & 15;
    const int lk = (lane >> 4) * 8;
    const int lq = (lane >> 4) * 4;

    const int sr = tid >> 2;
    const int sk = (tid & 3) * 8;

    const short* aptr  = (const short*)A + (size_t)(row0 + sr) * K + sk;
    const short* bptr0 = (const short*)Bm + (size_t)(col0 + sr) * K + sk;
    const short* bptr1 = (const short*)Bm + (size_t)(col0 + 64 + sr) * K + sk;

    f32x4 acc[2][4] = {};

    bf16x8 ra  = *(const bf16x8*)(aptr);
    bf16x8 rb0 = *(const bf16x8*)(bptr0);
    bf16x8 rb1 = *(const bf16x8*)(bptr1);

    for (int k0 = 0; k0 < K; k0 += 32) {
        *(bf16x8*)&As[sr][sk]      = ra;
        *(bf16x8*)&Bs[sr][sk]      = rb0;
        *(bf16x8*)&Bs[64 + sr][sk] = rb1;
        __syncthreads();
        if (k0 + 32 < K) {
            ra  = *(const bf16x8*)(aptr + k0 + 32);
            rb0 = *(const bf16x8*)(bptr0 + k0 + 32);
            rb1 = *(const bf16x8*)(bptr1 + k0 + 32);
        }
        bf16x8 af[2], bfr[4];
        #pragma unroll
        for (int i = 0; i < 2; ++i)
            af[i] = *(const bf16x8*)&As[wr + i*16 + lr][lk];
        #pragma unroll
        for (int j = 0; j < 4; ++j)
            bfr[j] = *(const bf16x8*)&Bs[wc + j*16 + lr][lk];
        #pragma unroll
        for (int i = 0; i < 2; ++i)
            #pragma unroll
            for (int j = 0; j < 4; ++j)
                acc[i][j] = __builtin_amdgcn_mfma_f32_16x16x32_bf16(af[i], bfr[j], acc[i][j], 0, 0, 0);
        __syncthreads();
    }

    #pragma unroll
    for (int j = 0; j < 4; ++j) {
        const int col = col0 + wc + j*16 + lr;
        const float bs = bias[col];
        #pragma unroll
        for (int i = 0; i < 2; ++i) {
            const int rowb = row0 + wr + i*16 + lq;
            #pragma unroll
            for (int r = 0; r < 4; ++r)
                C[(size_t)(rowb + r) * DMODEL + col] = acc[i][j][r] + bs;
        }
    }
}

// ============ parallel scan (CH=16, CL=8) ============
// passA: feature-split — grid (B, CH, 4) x 128 threads; block z owns features z*128..z*128+127.
__global__ __launch_bounds__(128, 1)
void scan_passA(const float* __restrict__ pc, const float* __restrict__ pr,
                const int* __restrict__ term, const float* __restrict__ tick_in,
                float* __restrict__ SPk, float* __restrict__ SPv4, float* __restrict__ SPv1)
{
    const int b = blockIdx.x, c = blockIdx.y;
    const int ftid = blockIdx.z * 128 + threadIdx.x;   // 0..511
    const int w = ftid >> 6, lane = ftid & 63;
    const int t0 = c * CL;

    __shared__ __align__(16) float cos_s[CL][4];
    const float tick_b = tick_in[b];
    if (threadIdx.x < CL * 4) {
        const int lt = threadIdx.x >> 2, r = threadIdx.x & 3;
        const float PI_F = 3.14159265358979323846f;
        const float omega[4] = {-PI_F, -PI_F/3.0f, PI_F/3.0f, PI_F};
        cos_s[lt][r] = cosf(((float)(t0 + lt + 1) + tick_b) * omega[r]);
    }
    __syncthreads();

    float Sk[4][4] = {}, Ss[4] = {}, Sv[4] = {};
    float Pd[4] = {1.f, 1.f, 1.f, 1.f};
    float Pv = 1.f;

    float ck, cv, cbt, cg, ctm; float4 cp1, cp3;
    auto loadA = [&](int lt, float& k, float& v, float& bt, float& g,
                     float4& p1, float4& p3, float& tm) {
        const int t = t0 + ((lt < CL) ? lt : CL - 1);
        const float* Pc = pc + (size_t)(t * B_SZ + b) * NCRIT;
        const float* Pr = pr + (size_t)(t * B_SZ + b) * NRESTP;
        k  = Pc[w*64 + lane];
        p1 = *(const float4*)(Pc + 1024 + w*4);
        v  = Pr[w*64 + lane];
        bt = Pr[512 + w*64 + lane];
        g  = Pr[1024 + w*64 + lane];
        p3 = *(const float4*)(Pr + 1536 + w*4);
        tm = (float)term[t * B_SZ + b];
    };
    loadA(0, ck, cv, cbt, cg, cp1, cp3, ctm);

    for (int lt = 0; lt < CL; ++lt) {
        float nk, nv, nbt, ng, ntm; float4 np1, np3;
        loadA(lt + 1, nk, nv, nbt, ng, np1, np3, ntm);

        const float mask = 1.f - ctm;
        const float4 cs4 = *(const float4*)&cos_s[lt][0];
        const float cosr[4] = {cs4.x, cs4.y, cs4.z, cs4.w};
        const float rk = fmaxf(ck, 0.f);
        const float sg = sigmoidf_(cg);
        const float p1v[4] = {cp1.x, cp1.y, cp1.z, cp1.w};
        const float p3v[4] = {cp3.x, cp3.y, cp3.z, cp3.w};

        #pragma unroll
        for (int e = 0; e < 4; ++e) {
            const float psi = rk * fmaxf(p1v[e], 0.f);
            const float gf  = sg * sigmoidf_(p3v[e]);
            const float kg  = psi * gf;
            const float dg  = (1.f - gf) * mask;
            #pragma unroll
            for (int r = 0; r < 4; ++r)
                Sk[r][e] = dg * Sk[r][e] + kg * cosr[r];
            Ss[e] = dg * Ss[e] + kg;
            Pd[e] *= dg;
        }
        const float bb = sigmoidf_(cbt);
        const float vg = cv * bb;
        const float db = (1.f - bb) * mask;
        #pragma unroll
        for (int r = 0; r < 4; ++r) Sv[r] = db * Sv[r] + vg * cosr[r];
        Pv *= db;

        ck = nk; cv = nv; cbt = nbt; cg = ng; cp1 = np1; cp3 = np3; ctm = ntm;
    }

    float* K = SPk + ((size_t)(b * CH + c) * 512 + ftid) * 24;
    #pragma unroll
    for (int r = 0; r < 4; ++r)
        *(float4*)(K + r*4) = make_float4(Sk[r][0], Sk[r][1], Sk[r][2], Sk[r][3]);
    *(float4*)(K + 16) = make_float4(Pd[0], Pd[1], Pd[2], Pd[3]);
    *(float4*)(K + 20) = make_float4(Ss[0], Ss[1], Ss[2], Ss[3]);
    *(float4*)(SPv4 + ((size_t)(b * CH + c) * 512 + ftid) * 4) =
        make_float4(Sv[0], Sv[1], Sv[2], Sv[3]);
    SPv1[(size_t)(b * CH + c) * 512 + ftid] = Pv;
}

// passB: feature-parallel carry combine (256 blocks, reg-prefetch)
__global__ __launch_bounds__(64, 4)
void scan_passB(float* __restrict__ SPk, float* __restrict__ SPv4,
                const float* __restrict__ SPv1,
                const float* __restrict__ fk_prev, const float* __restrict__ fv_prev,
                const float* __restrict__ fs_prev, const float* __restrict__ tick_in,
                float* __restrict__ out_fk, float* __restrict__ out_fv,
                float* __restrict__ out_fs, float* __restrict__ out_tick)
{
    const int b = blockIdx.x, w = blockIdx.y;
    const int lane = threadIdx.x;
    const int ftid = w * 64 + lane;
    const int f0 = lane << 2;

    float yk[4][4], ys[4], yv[4];
    #pragma unroll
    for (int r = 0; r < 4; ++r) {
        const float4 kk = *(const float4*)(fk_prev + (((size_t)b * R_N + r) * H_N + w) * FD_N + f0);
        yk[r][0] = kk.x; yk[r][1] = kk.y; yk[r][2] = kk.z; yk[r][3] = kk.w;
        yv[r] = fv_prev[(((size_t)b * R_N + r) * H_N + w) * DH_N + lane];
    }
    {
        const float4 ss = *(const float4*)(fs_prev + ((size_t)b * H_N + w) * FD_N + f0);
        ys[0] = ss.x; ys[1] = ss.y; ys[2] = ss.z; ys[3] = ss.w;
    }

    const size_t stride = (size_t)512 * 24;
    const size_t strideV = (size_t)512 * 4;
    float* K0 = SPk + ((size_t)(b * CH) * 512 + ftid) * 24;
    float* V0 = SPv4 + ((size_t)(b * CH) * 512 + ftid) * 4;
    const float* P0 = SPv1 + (size_t)(b * CH) * 512 + ftid;

    float4 S0 = *(float4*)(K0 + 0),  S1 = *(float4*)(K0 + 4);
    float4 S2 = *(float4*)(K0 + 8),  S3 = *(float4*)(K0 + 12);
    float4 P4 = *(float4*)(K0 + 16), Q4 = *(float4*)(K0 + 20);
    float4 Sv4 = *(float4*)V0;
    float  Pv  = P0[0];

    for (int c = 0; c < CH; ++c) {
        float* K = K0 + (size_t)c * stride;
        float* V = V0 + (size_t)c * strideV;

        const float4 cS0 = S0, cS1 = S1, cS2 = S2, cS3 = S3, cP4 = P4, cQ4 = Q4, cSv = Sv4;
        const float cPv = Pv;

        if (c + 1 < CH) {
            float* Kn = K0 + (size_t)(c + 1) * stride;
            float* Vn = V0 + (size_t)(c + 1) * strideV;
            S0 = *(float4*)(Kn + 0);  S1 = *(float4*)(Kn + 4);
            S2 = *(float4*)(Kn + 8);  S3 = *(float4*)(Kn + 12);
            P4 = *(float4*)(Kn + 16); Q4 = *(float4*)(Kn + 20);
            Sv4 = *(float4*)Vn;
            Pv  = P0[(size_t)(c + 1) * 512];
        }

        *(float4*)(K + 0)  = make_float4(yk[0][0], yk[0][1], yk[0][2], yk[0][3]);
        *(float4*)(K + 4)  = make_float4(yk[1][0], yk[1][1], yk[1][2], yk[1][3]);
        *(float4*)(K + 8)  = make_float4(yk[2][0], yk[2][1], yk[2][2], yk[2][3]);
        *(float4*)(K + 12) = make_float4(yk[3][0], yk[3][1], yk[3][2], yk[3][3]);
        *(float4*)(K + 20) = make_float4(ys[0], ys[1], ys[2], ys[3]);
        *(float4*)V        = make_float4(yv[0], yv[1], yv[2], yv[3]);

        const float S[4][4] = {{cS0.x,cS0.y,cS0.z,cS0.w}, {cS1.x,cS1.y,cS1.z,cS1.w},
                               {cS2.x,cS2.y,cS2.z,cS2.w}, {cS3.x,cS3.y,cS3.z,cS3.w}};
        const float Pd[4] = {cP4.x, cP4.y, cP4.z, cP4.w};
        const float Ssv[4] = {cQ4.x, cQ4.y, cQ4.z, cQ4.w};
        const float Svv[4] = {cSv.x, cSv.y, cSv.z, cSv.w};
        #pragma unroll
        for (int e = 0; e < 4; ++e) {
            #pragma unroll
            for (int r = 0; r < 4; ++r)
                yk[r][e] = S[r][e] + Pd[e] * yk[r][e];
            ys[e] = Ssv[e] + Pd[e] * ys[e];
        }
        #pragma unroll
        for (int r = 0; r < 4; ++r)
            yv[r] = Svv[r] + cPv * yv[r];
    }

    #pragma unroll
    for (int r = 0; r < 4; ++r) {
        *(float4*)(out_fk + (((size_t)b * R_N + r) * H_N + w) * FD_N + f0) =
            make_float4(yk[r][0], yk[r][1], yk[r][2], yk[r][3]);
        out_fv[(((size_t)b * R_N + r) * H_N + w) * DH_N + lane] = yv[r];
    }
    *(float4*)(out_fs + ((size_t)b * H_N + w) * FD_N + f0) =
        make_float4(ys[0], ys[1], ys[2], ys[3]);
    if (w == 0 && lane == 0) out_tick[b] = tick_in[b] + (float)T_LEN;
}

struct PF {
    float k[4], q[4], v[4], bt[4], g[4], tm[4];
    float4 p1[4], p2[4], p3[4];
};

__global__ __launch_bounds__(512, 1)
void scan_passC(const float* __restrict__ pc, const float* __restrict__ pr,
                const int* __restrict__ term, const float* __restrict__ tick_in,
                const float* __restrict__ SPk, const float* __restrict__ SPv4,
                __hip_bfloat16* __restrict__ attn)
{
    const int b = blockIdx.x, c = blockIdx.y;
    const int tid = threadIdx.x, w = tid >> 6, lane = tid & 63;
    const int tc0 = c * CL;

    __shared__ float red[2][4][8][4];
    __shared__ __align__(16) float cos_s[CL][4];

    const float tick_b = tick_in[b];
    if (tid < CL * 4) {
        const int lt = tid >> 2, r = tid & 3;
        const float PI_F = 3.14159265358979323846f;
        const float omega[4] = {-PI_F, -PI_F/3.0f, PI_F/3.0f, PI_F};
        cos_s[lt][r] = cosf(((float)(tc0 + lt + 1) + tick_b) * omega[r]);
    }

    float fk[4][4], fsv[4], fv[4];
    {
        const float* K = SPk + ((size_t)(b * CH + c) * 512 + tid) * 24;
        #pragma unroll
        for (int r = 0; r < 4; ++r) {
            const float4 kk = *(const float4*)(K + r*4);
            fk[r][0] = kk.x; fk[r][1] = kk.y; fk[r][2] = kk.z; fk[r][3] = kk.w;
        }
        const float4 s4 = *(const float4*)(K + 20);
        fsv[0] = s4.x; fsv[1] = s4.y; fsv[2] = s4.z; fsv[3] = s4.w;
        const float4 v4 = *(const float4*)(SPv4 + ((size_t)(b * CH + c) * 512 + tid) * 4);
        fv[0] = v4.x; fv[1] = v4.y; fv[2] = v4.z; fv[3] = v4.w;
    }

    auto prefetch = [&](PF& dst, int lt0) {
        #pragma unroll
        for (int s = 0; s < 4; ++s) {
            int lt = lt0 + s; lt = (lt < CL) ? lt : CL - 1;
            const int t = tc0 + lt;
            const float* Pc = pc + (size_t)(t * B_SZ + b) * NCRIT;
            const float* Pr = pr + (size_t)(t * B_SZ + b) * NRESTP;
            dst.k[s]  = Pc[w*64 + lane];
            dst.q[s]  = Pc[512 + w*64 + lane];
            dst.p1[s] = *(const float4*)(Pc + 1024 + w*4);
            dst.p2[s] = *(const float4*)(Pc + 1056 + w*4);
            dst.v[s]  = Pr[w*64 + lane];
            dst.bt[s] = Pr[512 + w*64 + lane];
            dst.g[s]  = Pr[1024 + w*64 + lane];
            dst.p3[s] = *(const float4*)(Pr + 1536 + w*4);
            dst.tm[s] = (float)term[t * B_SZ + b];
        }
    };

    auto round_body = [&](const PF& cur, int lt0, int P) {
        float sc[4][4], nr[4], fvs[4][4];
        #pragma unroll
        for (int s = 0; s < 4; ++s) {
            const float mask = 1.f - cur.tm[s];
            const float4 cs = *(const float4*)&cos_s[lt0 + s][0];
            const float cosr[4] = {cs.x, cs.y, cs.z, cs.w};
            const float rk = fmaxf(cur.k[s], 0.f);
            const float rq = fmaxf(cur.q[s], 0.f);
            const float sg = sigmoidf_(cur.g[s]);
            const float p1v[4] = {cur.p1[s].x, cur.p1[s].y, cur.p1[s].z, cur.p1[s].w};
            const float p2v[4] = {cur.p2[s].x, cur.p2[s].y, cur.p2[s].z, cur.p2[s].w};
            const float p3v[4] = {cur.p3[s].x, cur.p3[s].y, cur.p3[s].z, cur.p3[s].w};
            float phi[4], kg[4], dgv[4];
            float np = 0.f;
            #pragma unroll
            for (int e = 0; e < 4; ++e) {
                const float psi = rk * fmaxf(p1v[e], 0.f);
                phi[e] = rq * fmaxf(p2v[e], 0.f);
                const float gf = sg * sigmoidf_(p3v[e]);
                kg[e] = psi * gf;
                dgv[e] = (1.f - gf) * mask;
                fsv[e] = dgv[e] * fsv[e] + kg[e];
                np += fsv[e] * phi[e];
            }
            nr[s] = np;
            #pragma unroll
            for (int r = 0; r < R_N; ++r) {
                float ss = 0.f;
                #pragma unroll
                for (int e = 0; e < 4; ++e) {
                    fk[r][e] = dgv[e] * fk[r][e] + kg[e] * cosr[r];
                    ss += fk[r][e] * phi[e];
                }
                sc[s][r] = ss;
            }
            const float bb = sigmoidf_(cur.bt[s]);
            const float vg = cur.v[s] * bb;
            const float db = (1.f - bb) * mask;
            #pragma unroll
            for (int r = 0; r < R_N; ++r) { fv[r] = db * fv[r] + vg * cosr[r]; fvs[s][r] = fv[r]; }
        }
        #pragma unroll
        for (int off = 32; off >= 1; off >>= 1) {
            #pragma unroll
            for (int s = 0; s < 4; ++s) {
                #pragma unroll
                for (int r = 0; r < 4; ++r) sc[s][r] += __shfl_xor(sc[s][r], off);
                nr[s] += __shfl_xor(nr[s], off);
            }
        }
        if (lane == 0) {
            #pragma unroll
            for (int s = 0; s < 4; ++s)
                *(float4*)&red[P][s][w][0] = make_float4(sc[s][0], sc[s][1], sc[s][2], sc[s][3]);
        }
        __syncthreads();
        #pragma unroll
        for (int s = 0; s < 4; ++s) {
            float s0 = 0.f, s1 = 0.f, s2 = 0.f, s3 = 0.f;
            #pragma unroll
            for (int ww = 0; ww < 8; ++ww) {
                const float4 rv = *(const float4*)&red[P][s][ww][0];
                s0 += rv.x; s1 += rv.y; s2 += rv.z; s3 += rv.w;
            }
            const float kv = fvs[s][0]*s0 + fvs[s][1]*s1 + fvs[s][2]*s2 + fvs[s][3]*s3;
            attn[((size_t)(tc0 + lt0 + s) * B_SZ + b) * (H_N * DH_N) + tid] =
                __float2bfloat16(kv / (2.0f * R_N * nr[s] + EPS_F));
        }
    };

    PF Abuf, Bbuf;
    prefetch(Abuf, 0);
    __syncthreads();

    for (int lt0 = 0; lt0 < CL; lt0 += 8) {
        prefetch(Bbuf, lt0 + 4);
        round_body(Abuf, lt0, 0);
        prefetch(Abuf, lt0 + 8);
        round_body(Bbuf, lt0 + 4, 1);
    }
}

extern "C" void kernel_launch(void* const* d_in, const int* in_sizes, int n_in,
                              void* d_out, int out_size, void* d_ws, size_t ws_size,
                              hipStream_t stream)
{
    const float* inputs  = (const float*)d_in[0];
    const int*   term    = (const int*)  d_in[1];
    const float* fk_prev = (const float*)d_in[2];
    const float* fv_prev = (const float*)d_in[3];
    const float* fs_prev = (const float*)d_in[4];
    const float* tick    = (const float*)d_in[5];
    const float* Wf      = (const float*)d_in[6];
    const float* bf      = (const float*)d_in[7];
    const float* Wp      = (const float*)d_in[8];
    const float* bp      = (const float*)d_in[9];

    float* out      = (float*)d_out;
    float* out_fk   = out    + (size_t)T_LEN * B_SZ * DMODEL;
    float* out_fv   = out_fk + (size_t)B_SZ * R_N * H_N * FD_N;
    float* out_fs   = out_fv + (size_t)B_SZ * R_N * H_N * DH_N;
    float* out_tick = out_fs + (size_t)B_SZ * H_N * FD_N;

    char* ws = (char*)d_ws;
    float* proj_crit = (float*)ws;                       // 17.8 MB
    ws += (size_t)T_LEN * B_SZ * NCRIT * 4;
    float* proj_rest = (float*)ws;                       // 27.3 MB
    ws += (size_t)T_LEN * B_SZ * NRESTP * 4;
    __hip_bfloat16* attn_bf = (__hip_bfloat16*)ws;       // 4.2 MB
    ws += (size_t)T_LEN * B_SZ * H_N * DH_N * 2;
    __hip_bfloat16* Wp_bf = (__hip_bfloat16*)ws;         // 1 MB
    ws += (size_t)DMODEL * H_N * DH_N * 2;
    _Float16* Wch = (_Float16*)ws;                       // 2.23 MB
    ws += (size_t)NCRIT * DMODEL * 2;
    _Float16* Wcl = (_Float16*)ws;                       // 2.23 MB
    ws += (size_t)NCRIT * DMODEL * 2;
    float* bias_rest = (float*)ws;                       // 6.7 KB
    ws += (size_t)NRESTP * 4;
    char* uni = ws;
    _Float16* Xh      = (_Float16*)uni;
    _Float16* Xl      = (_Float16*)(uni + (size_t)T_LEN * B_SZ * DMODEL * 2);
    _Float16* Wrest_h = (_Float16*)(uni + (size_t)T_LEN * B_SZ * DMODEL * 4);
    float* SPk  = (float*)uni;
    float* SPv4 = (float*)(uni + (size_t)B_SZ * CH * 512 * 24 * 4);
    float* SPv1 = (float*)(uni + (size_t)B_SZ * CH * 512 * 28 * 4);

    // 0) all conversions, one launch
    cvt_fused<<<5312, 256, 0, stream>>>(
        inputs, Wf, bf, Wp, Xh, Xl, Wch, Wcl, Wrest_h, bias_rest, Wp_bf);

    // 1) projection GEMMs, fused launch; col-outer per-XCD swizzle; launch_bounds(256,4)
    gemm_proj<<<NB_CRIT + NB_REST, 256, 0, stream>>>(
        Xh, Xl, Wch, Wcl, Wrest_h, bf, bias_rest, proj_crit, proj_rest);

    // 2) parallel scan (passA feature-split: 2048 blocks of 128 threads)
    scan_passA<<<dim3(B_SZ, CH, 4), dim3(128), 0, stream>>>(
        proj_crit, proj_rest, term, tick, SPk, SPv4, SPv1);
    scan_passB<<<dim3(B_SZ, H_N), dim3(64), 0, stream>>>(
        SPk, SPv4, SPv1, fk_prev, fv_prev, fs_prev, tick,
        out_fk, out_fv, out_fs, out_tick);
    scan_passC<<<dim3(B_SZ, CH), dim3(512), 0, stream>>>(
        proj_crit, proj_rest, term, tick, SPk, SPv4, attn_bf);

    // 3) out = attn @ Wp^T + bp
    gemm_out<<<dim3(DMODEL / 128, (T_LEN * B_SZ) / 64), dim3(256), 0, stream>>>(
        attn_bf, Wp_bf, bp, out);
}